// Round 16
// baseline (2569.188 us; speedup 1.0000x reference)
//
#include <hip/hip_runtime.h>
#include <hip/hip_bf16.h>

#define B_    8
#define NG    16906
#define KSEL  2048
#define D_    256
#define H_    8
#define DH    32
#define M_    110
#define DEPTH_ 6
#define DFF_  1024
#define N_    2049
#define BN_   (B_*N_)
#define QS    768          // fused qkv row stride (shorts)
#define NC    8            // fctx chunks (blocks per (b,h))
#define NTILES 33          // ceil(2049/64)
#define CTXE  (M_*33)      // 3630 per (b,h)
#define CTXN2 (64*CTXE)    // 232320
#define NIT_TK 17          // ceil(16906/1024)

static constexpr float DN    = 0.42044820762685725f;  // 32^-0.25
static constexpr float DN2   = 0.17677669529663687f;  // 32^-0.5
static constexpr float RATIO = 0.09534625892455922f;  // 110^-0.5

typedef __attribute__((ext_vector_type(8))) short s8v;
typedef __attribute__((ext_vector_type(4))) float f4v;

__device__ __forceinline__ unsigned floatToOrdered(float f){
  unsigned b = __float_as_uint(f);
  return (b & 0x80000000u) ? ~b : (b | 0x80000000u);
}
__device__ __forceinline__ float orderedToFloat(unsigned u){
  unsigned b = (u & 0x80000000u) ? (u & 0x7FFFFFFFu) : ~u;
  return __uint_as_float(b);
}
__device__ __forceinline__ unsigned short f2us(float f){
  __hip_bfloat16 b = __float2bfloat16(f);
  return *reinterpret_cast<unsigned short*>(&b);
}
__device__ __forceinline__ float us2f(unsigned short u){
  return __uint_as_float(((unsigned)u) << 16);
}

// ---------------- top-k: radix select + fused per-batch sum/max ----------------
__global__ __launch_bounds__(1024) void topk_k(const float* __restrict__ expr,
                                               float* __restrict__ selected,
                                               float* __restrict__ bsum,
                                               float* __restrict__ bv0)
{
  __shared__ unsigned histw[16*256];
  __shared__ unsigned sPrefix;
  __shared__ int sKK;
  __shared__ unsigned cGT, cEQ;
  int b = blockIdx.x, tid = threadIdx.x;
  int wv = tid >> 6, lane = tid & 63;
  const float* row = expr + (long)b*NG;
  unsigned rb[NIT_TK];
  #pragma unroll
  for (int i = 0; i < NIT_TK; i++){
    int idx = tid + i*1024;
    rb[i] = (idx < NG) ? __float_as_uint(row[idx]) : 0u;
  }
  if (tid == 0){ sPrefix = 0u; sKK = KSEL; }
  for (int pass = 0; pass < 4; ++pass){
    int shift = 24 - pass*8;
    for (int i = tid; i < 16*256; i += 1024) histw[i] = 0u;
    __syncthreads();
    unsigned pref = sPrefix;
    unsigned kk  = (unsigned)sKK;
    #pragma unroll
    for (int i = 0; i < NIT_TK; i++){
      int idx = tid + i*1024;
      unsigned bits = rb[i];
      bool ok = (idx < NG) && ((pass == 0) || ((bits >> (shift + 8)) == pref));
      if (ok) atomicAdd(&histw[wv*256 + ((bits >> shift) & 255u)], 1u);
    }
    __syncthreads();
    if (tid < 256){
      unsigned s = 0;
      #pragma unroll
      for (int w = 0; w < 16; w++) s += histw[w*256 + tid];
      histw[tid] = s;
    }
    __syncthreads();
    unsigned* bufA = histw;
    unsigned* bufB = histw + 256;
    for (int d = 1; d < 256; d <<= 1){
      if (tid < 256)
        bufB[tid] = bufA[tid] + ((tid + d < 256) ? bufA[tid + d] : 0u);
      __syncthreads();
      unsigned* t = bufA; bufA = bufB; bufB = t;
    }
    if (tid < 256){
      unsigned sj  = bufA[tid];
      unsigned sj1 = (tid < 255) ? bufA[tid + 1] : 0u;
      if (sj >= kk && sj1 < kk){
        sPrefix = (pref << 8) | (unsigned)tid;
        sKK = (int)(kk - sj1);
      }
    }
    __syncthreads();
  }
  unsigned T = sPrefix; int needEQ = sKK; int base = KSEL - needEQ;
  if (tid == 0){ cGT = 0u; cEQ = 0u; }
  __syncthreads();
  #pragma unroll
  for (int i = 0; i < NIT_TK; i++){
    int idx = tid + i*1024;
    bool v = (idx < NG);
    unsigned bits = rb[i];
    bool gt = v && (bits > T);
    unsigned long long mgt = __ballot(gt);
    if (mgt){
      int leader = __ffsll((long long)mgt) - 1;
      unsigned wbase = 0;
      if (lane == leader) wbase = atomicAdd(&cGT, (unsigned)__popcll(mgt));
      wbase = __shfl(wbase, leader);
      if (gt){
        int pre = __popcll(mgt & ((1ULL << lane) - 1ULL));
        selected[(long)b*KSEL + wbase + pre] = __uint_as_float(bits);
      }
    }
    bool eq = v && (bits == T);
    unsigned long long meq = __ballot(eq);
    if (meq){
      int leader = __ffsll((long long)meq) - 1;
      unsigned wbase = 0;
      if (lane == leader) wbase = atomicAdd(&cEQ, (unsigned)__popcll(meq));
      wbase = __shfl(wbase, leader);
      if (eq){
        int pos = (int)wbase + __popcll(meq & ((1ULL << lane) - 1ULL));
        if (pos < needEQ) selected[(long)b*KSEL + base + pos] = __uint_as_float(bits);
      }
    }
  }
  // fused per-batch sum & max of the selected set (replaces nsum_k):
  // sum = sum(values > T) + needEQ * T ; max = row max (== max selected)
  float gsum = 0.f; unsigned gmax = 0u;
  #pragma unroll
  for (int i = 0; i < NIT_TK; i++){
    int idx = tid + i*1024;
    if (idx < NG){
      unsigned bits = rb[i];
      if (bits > T) gsum += __uint_as_float(bits);
      gmax = max(gmax, bits);            // valid: all values >= 0
    }
  }
  __syncthreads();                       // scatter done; reuse histw as scratch
  float*    fs = (float*)histw;          // [0..1023]
  unsigned* um = histw + 1024;           // [1024..2047]
  fs[tid] = gsum;
  um[tid] = gmax;
  __syncthreads();
  for (int k2 = 512; k2 > 0; k2 >>= 1){
    if (tid < k2){
      fs[tid] += fs[tid + k2];
      um[tid] = max(um[tid], um[tid + k2]);
    }
    __syncthreads();
  }
  if (tid == 0){
    bsum[b] = fs[0] + (float)needEQ * __uint_as_float(T);
    bv0[b]  = __uint_as_float(um[0]);
  }
}

// ---------------- global max of e = log1p(v0/sum*1e4) ----------------
__global__ __launch_bounds__(64) void emax_k(const float* __restrict__ bsum,
                                             const float* __restrict__ bv0,
                                             float* __restrict__ emaxp)
{
  int tid = threadIdx.x;
  float e = -INFINITY;
  if (tid < B_) e = log1pf(bv0[tid] / fmaxf(bsum[tid], 1e-12f) * 10000.0f);
  #pragma unroll
  for (int m = 1; m < 64; m <<= 1) e = fmaxf(e, __shfl_xor(e, m));
  if (tid == 0) emaxp[0] = e;
}

// ---------------- tokenize + embed: 4 rows per block ----------------
__global__ __launch_bounds__(256) void embed_k(const float* __restrict__ selected,
    const float* __restrict__ bsum, const float* __restrict__ emaxp,
    const float* __restrict__ temb, const float* __restrict__ cls,
    float* __restrict__ x)
{
  int rowi = blockIdx.x*4 + (threadIdx.x >> 6);
  int b = rowi / N_, n = rowi % N_;
  int lane = threadIdx.x & 63;
  const float* src;
  if (n == 0){
    src = cls;
  } else {
    float val = selected[(long)b*KSEL + (n - 1)];
    float e = log1pf(val / fmaxf(bsum[b], 1e-12f) * 10000.0f);
    float step = emaxp[0] / 7.0f;              // matches jnp.linspace step
    int cnt = 0;
    #pragma unroll
    for (int i = 0; i < 7; i++) cnt += (((float)i * step) < e) ? 1 : 0;  // searchsorted 'left'
    int tok = cnt > 6 ? 6 : cnt;
    src = temb + (long)tok * D_;
  }
  float4 o = *(const float4*)(src + lane*4);
  *(float4*)(x + (long)rowi*D_ + lane*4) = o;
}

// ---------------- LayerNorm: one wave per row, bf16 output ----------------
__global__ __launch_bounds__(256) void ln_k(const float* __restrict__ x,
    unsigned short* __restrict__ out,
    const float* __restrict__ g, const float* __restrict__ bb)
{
  int row = blockIdx.x*4 + (threadIdx.x >> 6);
  int lane = threadIdx.x & 63;
  float4 v = *(const float4*)(x + (long)row*D_ + lane*4);
  float s = v.x + v.y + v.z + v.w;
  float q = v.x*v.x + v.y*v.y + v.z*v.z + v.w*v.w;
  #pragma unroll
  for (int m = 1; m < 64; m <<= 1){ s += __shfl_xor(s, m); q += __shfl_xor(q, m); }
  float mu  = s * (1.0f/D_);
  float var = q * (1.0f/D_) - mu*mu;
  float inv = 1.0f / sqrtf(fmaxf(var, 0.f) + 1e-5f);
  float4 gu = *(const float4*)(g + lane*4);
  float4 bu = *(const float4*)(bb + lane*4);
  ushort4 o;
  o.x = f2us((v.x - mu)*inv*gu.x + bu.x);
  o.y = f2us((v.y - mu)*inv*gu.y + bu.y);
  o.z = f2us((v.z - mu)*inv*gu.z + bu.z);
  o.w = f2us((v.w - mu)*inv*gu.w + bu.w);
  *(ushort4*)(out + (long)row*D_ + lane*4) = o;
}

// ---------------- weight convert + transpose: dst[n][k] = bf16(src[k][n]) ----------------
__global__ __launch_bounds__(256) void wcvt_k(const float* __restrict__ src, long srcL,
    unsigned short* __restrict__ dst, long dstL, int K, int N)
{
  __shared__ float t[32][33];
  int n0 = blockIdx.x*32, k0 = blockIdx.y*32, L = blockIdx.z;
  int tx = threadIdx.x & 31, ty = threadIdx.x >> 5;
  const float* s = src + (long)L*srcL;
  for (int i = ty; i < 32; i += 8)
    t[i][tx] = s[(long)(k0+i)*N + n0 + tx];
  __syncthreads();
  unsigned short* d = dst + (long)L*dstL;
  for (int i = ty; i < 32; i += 8)
    d[(long)(n0 + i)*K + k0 + tx] = f2us(t[tx][i]);
}

// ---------------- proj convert + zero kmax slots ----------------
__global__ __launch_bounds__(256) void pcvt_k(const float* __restrict__ proj,
                                              unsigned short* __restrict__ projb,
                                              unsigned* __restrict__ kmaxb)
{
  int L = blockIdx.x;
  if (blockIdx.x == 0 && threadIdx.x < DEPTH_) kmaxb[threadIdx.x] = 0u;
  for (int i = threadIdx.x; i < 112*32; i += 256){
    int m = i >> 5, d = i & 31;
    float v = (m < M_) ? proj[(long)L*M_*DH + m*DH + d] : 0.f;
    projb[(long)L*112*32 + i] = f2us(v);
  }
}

// ---------------- bias concat: bqkv[L][768] = [bq|bk|bv] ----------------
__global__ __launch_bounds__(256) void bcat_k(const float* __restrict__ bq,
    const float* __restrict__ bk, const float* __restrict__ bv,
    float* __restrict__ bqkv)
{
  int L = blockIdx.x;
  for (int i = threadIdx.x; i < QS; i += 256){
    float v = (i < 256) ? bq[L*256 + i] : (i < 512) ? bk[L*256 + i - 256] : bv[L*256 + i - 512];
    bqkv[(long)L*QS + i] = v;
  }
}

// ---------------- bf16 MFMA GEMM: double-buffered LDS, one barrier per K-step ----------------
template<int ACT, int RES, int OUTBF>
__global__ __launch_bounds__(256) void bgemm_k(
    const unsigned short* __restrict__ A, long lda,
    const unsigned short* __restrict__ Bt,
    const float* __restrict__ bias,
    const float* __restrict__ res,
    float* __restrict__ Cf, unsigned short* __restrict__ Cb,
    int M, int Nn, int K)
{
  __shared__ __attribute__((aligned(16))) unsigned short smem[2*2*128*40];
  int tid = threadIdx.x;
  int colBlk = blockIdx.x*128, rowBlk = blockIdx.y*128;
  int w = tid >> 6, lane = tid & 63;
  int wrow = (w >> 1)*64, wcol = (w & 1)*64;
  int fr = lane & 15, fk = (lane >> 4)*8, fq = lane >> 4;
  int srh = tid >> 2, sk8 = (tid & 3)*8;

  f4v acc[4][4];
  #pragma unroll
  for (int r = 0; r < 4; r++)
    #pragma unroll
    for (int c = 0; c < 4; c++) acc[r][c] = (f4v){0.f, 0.f, 0.f, 0.f};

  s8v pa[2], pb[2];
  #pragma unroll
  for (int half = 0; half < 2; half++){
    int r = half*64 + srh;
    int ar = rowBlk + r;
    pa[half] = (ar < M) ? *(const s8v*)(A + (long)ar*lda + sk8) : (s8v){0,0,0,0,0,0,0,0};
    pb[half] = *(const s8v*)(Bt + (long)(colBlk + r)*K + sk8);
  }

  int it = 0;
  for (int kt = 0; kt < K; kt += 32, ++it){
    unsigned short* As = smem + (it & 1)*(2*128*40);
    unsigned short* Bs = As + 128*40;
    #pragma unroll
    for (int half = 0; half < 2; half++){
      int r = half*64 + srh;
      *(s8v*)&As[r*40 + sk8] = pa[half];
      *(s8v*)&Bs[r*40 + sk8] = pb[half];
    }
    __syncthreads();
    if (kt + 32 < K){
      int kn = kt + 32;
      #pragma unroll
      for (int half = 0; half < 2; half++){
        int r = half*64 + srh;
        int ar = rowBlk + r;
        pa[half] = (ar < M) ? *(const s8v*)(A + (long)ar*lda + kn + sk8) : (s8v){0,0,0,0,0,0,0,0};
        pb[half] = *(const s8v*)(Bt + (long)(colBlk + r)*K + kn + sk8);
      }
    }
    s8v a[4], b[4];
    #pragma unroll
    for (int r = 0; r < 4; r++) a[r] = *(s8v*)&As[(wrow + r*16 + fr)*40 + fk];
    #pragma unroll
    for (int c = 0; c < 4; c++) b[c] = *(s8v*)&Bs[(wcol + c*16 + fr)*40 + fk];
    #pragma unroll
    for (int r = 0; r < 4; r++)
      #pragma unroll
      for (int c = 0; c < 4; c++)
        acc[r][c] = __builtin_amdgcn_mfma_f32_16x16x32_bf16(a[r], b[c], acc[r][c], 0, 0, 0);
  }

  if (OUTBF){
    __syncthreads();
    unsigned short* Cs = smem;             // [128][132]
    #pragma unroll
    for (int c = 0; c < 4; c++){
      int col = wcol + c*16 + fr;
      float bz = bias[colBlk + col];
      #pragma unroll
      for (int r = 0; r < 4; r++){
        #pragma unroll
        for (int j = 0; j < 4; j++){
          int rrow = wrow + r*16 + fq*4 + j;
          float val = acc[r][c][j] + bz;
          if (ACT == 1) val = 0.5f * val * (1.0f + erff(val * 0.70710678118654752f));
          Cs[rrow*132 + col] = f2us(val);
        }
      }
    }
    __syncthreads();
    for (int ci = tid; ci < 128*16; ci += 256){
      int rrow = ci >> 4, ch = ci & 15;
      int grow = rowBlk + rrow;
      if (grow < M)
        *(s8v*)(Cb + (long)grow*Nn + colBlk + ch*8) = *(s8v*)&Cs[rrow*132 + ch*8];
    }
  } else {
    #pragma unroll
    for (int c = 0; c < 4; c++){
      int col = colBlk + wcol + c*16 + fr;
      float bz = bias[col];
      #pragma unroll
      for (int r = 0; r < 4; r++){
        #pragma unroll
        for (int j = 0; j < 4; j++){
          int row = rowBlk + wrow + r*16 + fq*4 + j;
          if (row < M){
            float val = acc[r][c][j] + bz;
            if (ACT == 1) val = 0.5f * val * (1.0f + erff(val * 0.70710678118654752f));
            if (RES) val += res[(long)row*Nn + col];
            Cf[(long)row*Nn + col] = val;
          }
        }
      }
    }
  }
}

// ---------------- fp32 GEMM (head only: 8 rows) ----------------
__global__ __launch_bounds__(256) void gemm_k(
    const float* __restrict__ A, long lda,
    const float* __restrict__ Bw, long ldb,
    const float* __restrict__ bias,
    float* __restrict__ Cf,
    int M, int Nn, int K)
{
  __shared__ float As[16][64];
  __shared__ float Bs[16][64];
  int tid = threadIdx.x;
  int tx = tid & 15, ty = tid >> 4;
  int rowBlk = blockIdx.x * 64, colBlk = blockIdx.y * 64;
  int am = tid >> 2, ak = (tid & 3) * 4;
  int bk = tid >> 4, bc = (tid & 15) * 4;
  float acc[4][4];
  #pragma unroll
  for (int i = 0; i < 4; i++)
    #pragma unroll
    for (int j = 0; j < 4; j++) acc[i][j] = 0.f;

  for (int kt = 0; kt < K; kt += 16){
    float4 av = make_float4(0.f, 0.f, 0.f, 0.f);
    int ar = rowBlk + am;
    if (ar < M) av = *(const float4*)(A + (long)ar*lda + kt + ak);
    As[ak+0][am] = av.x; As[ak+1][am] = av.y; As[ak+2][am] = av.z; As[ak+3][am] = av.w;
    float4 bv4 = *(const float4*)(Bw + (long)(kt + bk)*ldb + colBlk + bc);
    Bs[bk][bc+0] = bv4.x; Bs[bk][bc+1] = bv4.y;
    Bs[bk][bc+2] = bv4.z; Bs[bk][bc+3] = bv4.w;
    __syncthreads();
    #pragma unroll
    for (int kk = 0; kk < 16; kk++){
      float4 a4 = *(const float4*)&As[kk][ty*4];
      float4 b4 = *(const float4*)&Bs[kk][tx*4];
      acc[0][0] += a4.x*b4.x; acc[0][1] += a4.x*b4.y; acc[0][2] += a4.x*b4.z; acc[0][3] += a4.x*b4.w;
      acc[1][0] += a4.y*b4.x; acc[1][1] += a4.y*b4.y; acc[1][2] += a4.y*b4.z; acc[1][3] += a4.y*b4.w;
      acc[2][0] += a4.z*b4.x; acc[2][1] += a4.z*b4.y; acc[2][2] += a4.z*b4.z; acc[2][3] += a4.z*b4.w;
      acc[3][0] += a4.w*b4.x; acc[3][1] += a4.w*b4.y; acc[3][2] += a4.w*b4.z; acc[3][3] += a4.w*b4.w;
    }
    __syncthreads();
  }
  int r0 = rowBlk + ty*4, c0 = colBlk + tx*4;
  float bz[4];
  #pragma unroll
  for (int j = 0; j < 4; j++) bz[j] = bias[c0 + j];
  #pragma unroll
  for (int i = 0; i < 4; i++){
    int r = r0 + i;
    if (r < M){
      #pragma unroll
      for (int j = 0; j < 4; j++)
        Cf[(long)r*Nn + c0 + j] = acc[i][j] + bz[j];
    }
  }
}

// ---------------- kmax via MFMA (k slice of bf16 qkv) ----------------
__global__ __launch_bounds__(256) void kmax2_k(const unsigned short* __restrict__ qkvb,
    const unsigned short* __restrict__ projb, unsigned* __restrict__ kmaxb)
{
  __shared__ __attribute__((aligned(16))) unsigned short ks[64*40];
  __shared__ float red[4];
  int t = blockIdx.x, h = blockIdx.y, b = blockIdx.z;
  int tid = threadIdx.x, w = tid >> 6, lane = tid & 63;
  int fr = lane & 15, fq = lane >> 4, fk = fq*8;
  int n0 = t*64;
  {
    int tok = tid >> 2, d8 = (tid & 3)*8;
    int n = n0 + tok;
    bool vld = (n < N_);
    s8v kv8 = vld ? *(const s8v*)(qkvb + ((long)(b*N_ + n))*QS + 256 + h*DH + d8)
                  : (s8v){0,0,0,0,0,0,0,0};
    *(s8v*)&ks[tok*40 + d8] = kv8;
  }
  __syncthreads();
  s8v bk_ = *(s8v*)&ks[(w*16 + fr)*40 + fk];
  float mx = -INFINITY;
  int n_ = w*16 + fr;
  bool nv = (n0 + n_ < N_);
  #pragma unroll
  for (int mt = 0; mt < 7; mt++){
    s8v ap = *(const s8v*)(projb + (mt*16 + fr)*32 + fk);
    f4v z = (f4v){0.f,0.f,0.f,0.f};
    f4v xd = __builtin_amdgcn_mfma_f32_16x16x32_bf16(ap, bk_, z, 0, 0, 0);
    #pragma unroll
    for (int j = 0; j < 4; j++){
      int m = mt*16 + fq*4 + j;
      float v = (nv && m < M_) ? xd[j]*DN : -INFINITY;
      mx = fmaxf(mx, v);
    }
  }
  #pragma unroll
  for (int mk = 1; mk < 64; mk <<= 1) mx = fmaxf(mx, __shfl_xor(mx, mk));
  if (lane == 0) red[w] = mx;
  __syncthreads();
  if (tid == 0){
    float g = fmaxf(fmaxf(red[0], red[1]), fmaxf(red[2], red[3]));
    atomicMax(kmaxb, floatToOrdered(g));
  }
}

// ---------------- fused ctx via double MFMA (bf16 qkv) ----------------
__global__ __launch_bounds__(256) void fctx_k(const unsigned short* __restrict__ qkvb,
    const unsigned short* __restrict__ projb,
    const unsigned* __restrict__ kmaxb, float* __restrict__ partials)
{
  __shared__ __attribute__((aligned(16))) unsigned short ks[64*40];
  __shared__ __attribute__((aligned(16))) unsigned short vt[48*72];
  __shared__ __attribute__((aligned(16))) unsigned short kps[112*72];
  __shared__ float diags[64];
  int c = blockIdx.x, h = blockIdx.y, b = blockIdx.z;
  int tid = threadIdx.x, w = tid >> 6, lane = tid & 63;
  int fr = lane & 15, fq = lane >> 4, fk = fq*8;
  float kmax = orderedToFloat(kmaxb[0]);

  for (int i = tid; i < 15*72; i += 256) vt[33*72 + i] = 0;
  if (tid < 64) vt[32*72 + tid] = f2us(1.0f);

  s8v ap[7];
  #pragma unroll
  for (int mt = 0; mt < 7; mt++)
    ap[mt] = *(const s8v*)(projb + (mt*16 + fr)*32 + fk);

  int mt0 = w, mt1 = w + 4;
  f4v acc0[3], acc1[3];
  #pragma unroll
  for (int dt = 0; dt < 3; dt++){ acc0[dt] = (f4v){0.f,0.f,0.f,0.f}; acc1[dt] = (f4v){0.f,0.f,0.f,0.f}; }

  int stok = tid >> 2, sd8 = (tid & 3)*8;
  for (int t = c; t < NTILES; t += NC){
    int n0 = t*64;
    __syncthreads();
    {
      int n = n0 + stok;
      bool vld = (n < N_);
      long gb = ((long)(b*N_ + (vld ? n : 0)))*QS + h*DH + sd8;
      s8v kv8 = vld ? *(const s8v*)(qkvb + gb + 256) : (s8v){0,0,0,0,0,0,0,0};
      s8v vv8 = vld ? *(const s8v*)(qkvb + gb + 512) : (s8v){0,0,0,0,0,0,0,0};
      *(s8v*)&ks[stok*40 + sd8] = kv8;
      #pragma unroll
      for (int j = 0; j < 8; j++)
        vt[(sd8 + j)*72 + stok] = (unsigned short)vv8[j];
      float sq = 0.f;
      #pragma unroll
      for (int j = 0; j < 8; j++){
        float kx = us2f((unsigned short)kv8[j]);
        sq += kx*kx;
      }
      sq += __shfl_xor(sq, 1); sq += __shfl_xor(sq, 2);
      if ((tid & 3) == 0) diags[stok] = 0.5f * DN2 * sq;
    }
    __syncthreads();
    s8v bk_ = *(s8v*)&ks[(w*16 + fr)*40 + fk];
    int n_ = w*16 + fr;
    bool nv = (n0 + n_ < N_);
    float dgn = diags[n_];
    #pragma unroll
    for (int mt = 0; mt < 7; mt++){
      f4v z = (f4v){0.f,0.f,0.f,0.f};
      f4v xd = __builtin_amdgcn_mfma_f32_16x16x32_bf16(ap[mt], bk_, z, 0, 0, 0);
      #pragma unroll
      for (int j = 0; j < 4; j++){
        float kp = nv ? RATIO*(expf(xd[j]*DN - dgn - kmax) + 1e-3f) : 0.f;
        kps[(mt*16 + fq*4 + j)*72 + n_] = f2us(kp);
      }
    }
    __syncthreads();
    #pragma unroll
    for (int kst = 0; kst < 2; kst++){
      int ko = kst*32 + fk;
      s8v b0 = *(s8v*)&vt[( 0 + fr)*72 + ko];
      s8v b1 = *(s8v*)&vt[(16 + fr)*72 + ko];
      s8v b2 = *(s8v*)&vt[(32 + fr)*72 + ko];
      s8v a0 = *(s8v*)&kps[(mt0*16 + fr)*72 + ko];
      acc0[0] = __builtin_amdgcn_mfma_f32_16x16x32_bf16(a0, b0, acc0[0], 0, 0, 0);
      acc0[1] = __builtin_amdgcn_mfma_f32_16x16x32_bf16(a0, b1, acc0[1], 0, 0, 0);
      acc0[2] = __builtin_amdgcn_mfma_f32_16x16x32_bf16(a0, b2, acc0[2], 0, 0, 0);
      if (mt1 < 7){
        s8v a1 = *(s8v*)&kps[(mt1*16 + fr)*72 + ko];
        acc1[0] = __builtin_amdgcn_mfma_f32_16x16x32_bf16(a1, b0, acc1[0], 0, 0, 0);
        acc1[1] = __builtin_amdgcn_mfma_f32_16x16x32_bf16(a1, b1, acc1[1], 0, 0, 0);
        acc1[2] = __builtin_amdgcn_mfma_f32_16x16x32_bf16(a1, b2, acc1[2], 0, 0, 0);
      }
    }
  }
  long pb = ((long)c*64 + (b*H_ + h))*CTXE;
  #pragma unroll
  for (int dt = 0; dt < 3; dt++){
    int d = dt*16 + fr;
    if (d < 33){
      #pragma unroll
      for (int j = 0; j < 4; j++){
        int m0 = mt0*16 + fq*4 + j;
        if (m0 < M_) partials[pb + m0*33 + d] = acc0[dt][j];
        if (mt1 < 7){
          int m1 = mt1*16 + fq*4 + j;
          if (m1 < M_) partials[pb + m1*33 + d] = acc1[dt][j];
        }
      }
    }
  }
}

// ---------------- attn v3: full-MFMA query side; sums ctx partials during staging ----------------
__global__ __launch_bounds__(256) void attn3_k(const unsigned short* __restrict__ qkvb,
    const float* __restrict__ partials, const unsigned short* __restrict__ projb,
    unsigned short* __restrict__ ob)
{
  __shared__ __attribute__((aligned(16))) unsigned short qs[64*40];
  __shared__ __attribute__((aligned(16))) unsigned short qps[64*136];
  __shared__ __attribute__((aligned(16))) unsigned short cst[48*136];
  __shared__ float diags[64];
  __shared__ float dens[64];
  int t = blockIdx.x, h = blockIdx.y, b = blockIdx.z;
  int tid = threadIdx.x, w = tid >> 6, lane = tid & 63;
  int fr = lane & 15, fq = lane >> 4, fk = fq*8;
  int n0 = t*64;
  long cbase = ((long)(b*H_ + h))*CTXE;

  for (int i = tid; i < 64*16; i += 256)
    qps[(i >> 4)*136 + 112 + (i & 15)] = 0;

  {
    int tok = tid >> 2, d8 = (tid & 3)*8;
    int n = n0 + tok;
    bool vld = (n < N_);
    s8v qv8 = vld ? *(const s8v*)(qkvb + ((long)(b*N_ + n))*QS + h*DH + d8)
                  : (s8v){0,0,0,0,0,0,0,0};
    *(s8v*)&qs[tok*40 + d8] = qv8;
    float sq = 0.f;
    #pragma unroll
    for (int j = 0; j < 8; j++){
      float qx = us2f((unsigned short)qv8[j]);
      sq += qx*qx;
    }
    sq += __shfl_xor(sq, 1); sq += __shfl_xor(sq, 2);
    if ((tid & 3) == 0) diags[tok] = 0.5f * DN2 * sq;
  }
  // ctx staging: sum NC partial chunks inline (replaces ctxred2_k)
  for (int i = tid; i < 48*128; i += 256){
    int d = i >> 7, m = i & 127;
    float v = 0.f;
    if (d < 33 && m < M_){
      long pbase = cbase + (long)m*33 + d;
      #pragma unroll
      for (int c = 0; c < NC; c++) v += partials[(long)c*CTXN2 + pbase];
    }
    cst[d*136 + m] = f2us(v);
  }
  __syncthreads();

  s8v bq_ = *(s8v*)&qs[(w*16 + fr)*40 + fk];
  int n_ = w*16 + fr;
  bool nv = (n0 + n_ < N_);
  float dgn = diags[n_];
  f4v xdv[7];
  #pragma unroll
  for (int mt = 0; mt < 7; mt++){
    s8v ap = *(const s8v*)(projb + (mt*16 + fr)*32 + fk);
    f4v z = (f4v){0.f,0.f,0.f,0.f};
    xdv[mt] = __builtin_amdgcn_mfma_f32_16x16x32_bf16(ap, bq_, z, 0, 0, 0);
  }
  float mx = -INFINITY;
  #pragma unroll
  for (int mt = 0; mt < 7; mt++)
    #pragma unroll
    for (int j = 0; j < 4; j++){
      int m = mt*16 + fq*4 + j;
      if (m < M_) mx = fmaxf(mx, xdv[mt][j]*DN);
    }
  mx = fmaxf(mx, __shfl_xor(mx, 16));
  mx = fmaxf(mx, __shfl_xor(mx, 32));
  #pragma unroll
  for (int mt = 0; mt < 7; mt++)
    #pragma unroll
    for (int j = 0; j < 4; j++){
      int m = mt*16 + fq*4 + j;
      float qp = (nv && m < M_) ? RATIO*(expf(xdv[mt][j]*DN - dgn - mx) + 1e-3f) : 0.f;
      qps[n_*136 + m] = f2us(qp);
    }
  __syncthreads();

  f4v acc[3];
  acc[0] = (f4v){0,0,0,0}; acc[1] = (f4v){0,0,0,0}; acc[2] = (f4v){0,0,0,0};
  #pragma unroll
  for (int ks = 0; ks < 4; ks++){
    int ko = ks*32 + fk;
    s8v bqp = *(s8v*)&qps[(w*16 + fr)*136 + ko];
    #pragma unroll
    for (int dt = 0; dt < 3; dt++){
      s8v ac = *(s8v*)&cst[(dt*16 + fr)*136 + ko];
      acc[dt] = __builtin_amdgcn_mfma_f32_16x16x32_bf16(ac, bqp, acc[dt], 0, 0, 0);
    }
  }
  if (fq == 0) dens[n_] = acc[2][0];
  __syncthreads();
  float dinv = 1.0f / dens[n_];
  if (nv){
    long obase = ((long)(b*N_ + n0 + n_))*D_ + h*DH;
    #pragma unroll
    for (int dt = 0; dt < 2; dt++){
      ushort4 wv;
      wv.x = f2us(acc[dt][0]*dinv);
      wv.y = f2us(acc[dt][1]*dinv);
      wv.z = f2us(acc[dt][2]*dinv);
      wv.w = f2us(acc[dt][3]*dinv);
      *(ushort4*)(ob + obase + dt*16 + fq*4) = wv;
    }
  }
}

// ---------------- host ----------------
extern "C" void kernel_launch(void* const* d_in, const int* in_sizes, int n_in,
                              void* d_out, int out_size, void* d_ws, size_t ws_size,
                              hipStream_t stream)
{
  const float* expr = (const float*)d_in[0];
  const float* temb = (const float*)d_in[1];
  const float* cls  = (const float*)d_in[2];
  const float* ln1g = (const float*)d_in[3];
  const float* ln1b = (const float*)d_in[4];
  const float* Wq   = (const float*)d_in[5];
  const float* bq   = (const float*)d_in[6];
  const float* Wk   = (const float*)d_in[7];
  const float* bk   = (const float*)d_in[8];
  const float* Wv   = (const float*)d_in[9];
  const float* bv   = (const float*)d_in[10];
  const float* Wo   = (const float*)d_in[11];
  const float* bo   = (const float*)d_in[12];
  const float* ln2g = (const float*)d_in[13];
  const float* ln2b = (const float*)d_in[14];
  const float* W1   = (const float*)d_in[15];
  const float* b1   = (const float*)d_in[16];
  const float* W2   = (const float*)d_in[17];
  const float* b2   = (const float*)d_in[18];
  const float* proj = (const float*)d_in[19];
  const float* Wp   = (const float*)d_in[20];
  const float* bp   = (const float*)d_in[21];
  (void)in_sizes; (void)n_in; (void)out_size; (void)ws_size;

  char* w = (char*)d_ws;
  size_t off = 0;
  auto alloc = [&](size_t bytes) -> char* {
    char* p = w + off;
    off = (off + bytes + 255) & ~(size_t)255;
    return p;
  };
  float*    selected = (float*)alloc((size_t)B_*KSEL*4);
  float*    bsum     = (float*)alloc(B_*4);
  float*    bv0      = (float*)alloc(B_*4);
  float*    emaxp    = (float*)alloc(4);
  unsigned* kmaxb    = (unsigned*)alloc(DEPTH_*4);
  float*          x  = (float*)alloc((size_t)BN_*D_*4);
  unsigned short* h  = (unsigned short*)alloc((size_t)BN_*D_*2);
  unsigned short* qkvb = (unsigned short*)alloc((size_t)BN_*DFF_*2);  // qkv bf16 (stride QS); ffi aliases (stride 1024)
  float*     partials = (float*)alloc((size_t)NC*CTXN2*4);            // own alloc (attn3 writes h while reading these)
  unsigned short* Wqkvt = (unsigned short*)alloc((size_t)DEPTH_*QS*D_*2);
  unsigned short* Wot = (unsigned short*)alloc((size_t)DEPTH_*D_*D_*2);
  unsigned short* W1t = (unsigned short*)alloc((size_t)DEPTH_*D_*DFF_*2);
  unsigned short* W2t = (unsigned short*)alloc((size_t)DEPTH_*DFF_*D_*2);
  unsigned short* projb = (unsigned short*)alloc((size_t)DEPTH_*112*32*2);
  float*    bqkv     = (float*)alloc((size_t)DEPTH_*QS*4);
  unsigned short* ffi = qkvb;                  // bf16 [BN][1024] aliases qkv (dead during FFN)

  wcvt_k<<<dim3(8, 8, DEPTH_),  256, 0, stream>>>(Wq, (long)D_*D_, Wqkvt + 0,      (long)QS*D_, D_, D_);
  wcvt_k<<<dim3(8, 8, DEPTH_),  256, 0, stream>>>(Wk, (long)D_*D_, Wqkvt + 256*D_, (long)QS*D_, D_, D_);
  wcvt_k<<<dim3(8, 8, DEPTH_),  256, 0, stream>>>(Wv, (long)D_*D_, Wqkvt + 512*D_, (long)QS*D_, D_, D_);
  wcvt_k<<<dim3(8, 8, DEPTH_),  256, 0, stream>>>(Wo, (long)D_*D_,   Wot, (long)D_*D_,   D_, D_);
  wcvt_k<<<dim3(32, 8, DEPTH_), 256, 0, stream>>>(W1, (long)D_*DFF_, W1t, (long)D_*DFF_, D_, DFF_);
  wcvt_k<<<dim3(8, 32, DEPTH_), 256, 0, stream>>>(W2, (long)DFF_*D_, W2t, (long)DFF_*D_, DFF_, D_);
  pcvt_k<<<DEPTH_, 256, 0, stream>>>(proj, projb, kmaxb);
  bcat_k<<<DEPTH_, 256, 0, stream>>>(bq, bk, bv, bqkv);

  topk_k<<<B_, 1024, 0, stream>>>(expr, selected, bsum, bv0);
  emax_k<<<1, 64, 0, stream>>>(bsum, bv0, emaxp);
  embed_k<<<BN_/4, 256, 0, stream>>>(selected, bsum, emaxp, temb, cls, x);

  for (int L = 0; L < DEPTH_; L++){
    const unsigned short* pjb = projb + (size_t)L*112*32;
    ln_k<<<BN_/4, 256, 0, stream>>>(x, h, ln1g + L*D_, ln1b + L*D_);
    bgemm_k<0,0,1><<<dim3(6,129), 256, 0, stream>>>(h, D_, Wqkvt + (size_t)L*QS*D_, bqkv + (size_t)L*QS, nullptr, nullptr, qkvb, BN_, QS, D_);
    kmax2_k<<<dim3(NTILES, H_, B_), 256, 0, stream>>>(qkvb, pjb, kmaxb + L);
    fctx_k<<<dim3(NC, H_, B_), 256, 0, stream>>>(qkvb, pjb, kmaxb + L, partials);
    attn3_k<<<dim3(NTILES, H_, B_), 256, 0, stream>>>(qkvb, partials, pjb, h);   // o -> h (bf16)
    bgemm_k<0,1,0><<<dim3(2,129), 256, 0, stream>>>(h, D_, Wot + (size_t)L*D_*D_, bo + L*D_, x, x, nullptr, BN_, D_, D_);
    ln_k<<<BN_/4, 256, 0, stream>>>(x, h, ln2g + L*D_, ln2b + L*D_);
    bgemm_k<1,0,1><<<dim3(8,129), 256, 0, stream>>>(h, D_, W1t + (size_t)L*D_*DFF_, b1 + L*DFF_, nullptr, nullptr, ffi, BN_, DFF_, D_);
    bgemm_k<0,1,0><<<dim3(2,129), 256, 0, stream>>>(ffi, DFF_, W2t + (size_t)L*DFF_*D_, b2 + L*D_, x, x, nullptr, BN_, D_, DFF_);
  }
  gemm_k<<<dim3(1,4), 256, 0, stream>>>(x, (long)N_*D_, Wp, D_, bp,
                                        (float*)d_out, B_, D_, D_);
}

// Round 17
// 1326.909 us; speedup vs baseline: 1.9362x; 1.9362x over previous
//
#include <hip/hip_runtime.h>
#include <hip/hip_bf16.h>

#define B_    8
#define NG    16906
#define KSEL  2048
#define D_    256
#define H_    8
#define DH    32
#define M_    110
#define DEPTH_ 6
#define DFF_  1024
#define N_    2049
#define BN_   (B_*N_)
#define QS    768          // fused qkv row stride (shorts)
#define NC    8            // fctx chunks (blocks per (b,h))
#define NTILES 33          // ceil(2049/64)
#define CTXE  (M_*33)      // 3630 per (b,h)
#define CTXN2 (64*CTXE)    // 232320
#define NIT_TK 17          // ceil(16906/1024)

static constexpr float DN    = 0.42044820762685725f;  // 32^-0.25
static constexpr float DN2   = 0.17677669529663687f;  // 32^-0.5
static constexpr float RATIO = 0.09534625892455922f;  // 110^-0.5

typedef __attribute__((ext_vector_type(8))) short s8v;
typedef __attribute__((ext_vector_type(4))) float f4v;

__device__ __forceinline__ unsigned floatToOrdered(float f){
  unsigned b = __float_as_uint(f);
  return (b & 0x80000000u) ? ~b : (b | 0x80000000u);
}
__device__ __forceinline__ float orderedToFloat(unsigned u){
  unsigned b = (u & 0x80000000u) ? (u & 0x7FFFFFFFu) : ~u;
  return __uint_as_float(b);
}
__device__ __forceinline__ unsigned short f2us(float f){
  __hip_bfloat16 b = __float2bfloat16(f);
  return *reinterpret_cast<unsigned short*>(&b);
}
__device__ __forceinline__ float us2f(unsigned short u){
  return __uint_as_float(((unsigned)u) << 16);
}

// ---------------- top-k: radix select + fused per-batch sum/max ----------------
__global__ __launch_bounds__(1024) void topk_k(const float* __restrict__ expr,
                                               float* __restrict__ selected,
                                               float* __restrict__ bsum,
                                               float* __restrict__ bv0)
{
  __shared__ unsigned histw[16*256];
  __shared__ unsigned sPrefix;
  __shared__ int sKK;
  __shared__ unsigned cGT, cEQ;
  int b = blockIdx.x, tid = threadIdx.x;
  int wv = tid >> 6, lane = tid & 63;
  const float* row = expr + (long)b*NG;
  unsigned rb[NIT_TK];
  #pragma unroll
  for (int i = 0; i < NIT_TK; i++){
    int idx = tid + i*1024;
    rb[i] = (idx < NG) ? __float_as_uint(row[idx]) : 0u;
  }
  if (tid == 0){ sPrefix = 0u; sKK = KSEL; }
  for (int pass = 0; pass < 4; ++pass){
    int shift = 24 - pass*8;
    for (int i = tid; i < 16*256; i += 1024) histw[i] = 0u;
    __syncthreads();
    unsigned pref = sPrefix;
    unsigned kk  = (unsigned)sKK;
    #pragma unroll
    for (int i = 0; i < NIT_TK; i++){
      int idx = tid + i*1024;
      unsigned bits = rb[i];
      bool ok = (idx < NG) && ((pass == 0) || ((bits >> (shift + 8)) == pref));
      if (ok) atomicAdd(&histw[wv*256 + ((bits >> shift) & 255u)], 1u);
    }
    __syncthreads();
    if (tid < 256){
      unsigned s = 0;
      #pragma unroll
      for (int w = 0; w < 16; w++) s += histw[w*256 + tid];
      histw[tid] = s;
    }
    __syncthreads();
    unsigned* bufA = histw;
    unsigned* bufB = histw + 256;
    for (int d = 1; d < 256; d <<= 1){
      if (tid < 256)
        bufB[tid] = bufA[tid] + ((tid + d < 256) ? bufA[tid + d] : 0u);
      __syncthreads();
      unsigned* t = bufA; bufA = bufB; bufB = t;
    }
    if (tid < 256){
      unsigned sj  = bufA[tid];
      unsigned sj1 = (tid < 255) ? bufA[tid + 1] : 0u;
      if (sj >= kk && sj1 < kk){
        sPrefix = (pref << 8) | (unsigned)tid;
        sKK = (int)(kk - sj1);
      }
    }
    __syncthreads();
  }
  unsigned T = sPrefix; int needEQ = sKK; int base = KSEL - needEQ;
  if (tid == 0){ cGT = 0u; cEQ = 0u; }
  __syncthreads();
  #pragma unroll
  for (int i = 0; i < NIT_TK; i++){
    int idx = tid + i*1024;
    bool v = (idx < NG);
    unsigned bits = rb[i];
    bool gt = v && (bits > T);
    unsigned long long mgt = __ballot(gt);
    if (mgt){
      int leader = __ffsll((long long)mgt) - 1;
      unsigned wbase = 0;
      if (lane == leader) wbase = atomicAdd(&cGT, (unsigned)__popcll(mgt));
      wbase = __shfl(wbase, leader);
      if (gt){
        int pre = __popcll(mgt & ((1ULL << lane) - 1ULL));
        selected[(long)b*KSEL + wbase + pre] = __uint_as_float(bits);
      }
    }
    bool eq = v && (bits == T);
    unsigned long long meq = __ballot(eq);
    if (meq){
      int leader = __ffsll((long long)meq) - 1;
      unsigned wbase = 0;
      if (lane == leader) wbase = atomicAdd(&cEQ, (unsigned)__popcll(meq));
      wbase = __shfl(wbase, leader);
      if (eq){
        int pos = (int)wbase + __popcll(meq & ((1ULL << lane) - 1ULL));
        if (pos < needEQ) selected[(long)b*KSEL + base + pos] = __uint_as_float(bits);
      }
    }
  }
  // fused per-batch sum & max (replaces nsum_k): sum = sum(>T) + needEQ*T; max = row max
  float gsum = 0.f; unsigned gmax = 0u;
  #pragma unroll
  for (int i = 0; i < NIT_TK; i++){
    int idx = tid + i*1024;
    if (idx < NG){
      unsigned bits = rb[i];
      if (bits > T) gsum += __uint_as_float(bits);
      gmax = max(gmax, bits);
    }
  }
  __syncthreads();
  float*    fs = (float*)histw;
  unsigned* um = histw + 1024;
  fs[tid] = gsum;
  um[tid] = gmax;
  __syncthreads();
  for (int k2 = 512; k2 > 0; k2 >>= 1){
    if (tid < k2){
      fs[tid] += fs[tid + k2];
      um[tid] = max(um[tid], um[tid + k2]);
    }
    __syncthreads();
  }
  if (tid == 0){
    bsum[b] = fs[0] + (float)needEQ * __uint_as_float(T);
    bv0[b]  = __uint_as_float(um[0]);
  }
}

// ---------------- global max of e = log1p(v0/sum*1e4) ----------------
__global__ __launch_bounds__(64) void emax_k(const float* __restrict__ bsum,
                                             const float* __restrict__ bv0,
                                             float* __restrict__ emaxp)
{
  int tid = threadIdx.x;
  float e = -INFINITY;
  if (tid < B_) e = log1pf(bv0[tid] / fmaxf(bsum[tid], 1e-12f) * 10000.0f);
  #pragma unroll
  for (int m = 1; m < 64; m <<= 1) e = fmaxf(e, __shfl_xor(e, m));
  if (tid == 0) emaxp[0] = e;
}

// ---------------- tokenize + embed: 4 rows per block ----------------
__global__ __launch_bounds__(256) void embed_k(const float* __restrict__ selected,
    const float* __restrict__ bsum, const float* __restrict__ emaxp,
    const float* __restrict__ temb, const float* __restrict__ cls,
    float* __restrict__ x)
{
  int rowi = blockIdx.x*4 + (threadIdx.x >> 6);
  int b = rowi / N_, n = rowi % N_;
  int lane = threadIdx.x & 63;
  const float* src;
  if (n == 0){
    src = cls;
  } else {
    float val = selected[(long)b*KSEL + (n - 1)];
    float e = log1pf(val / fmaxf(bsum[b], 1e-12f) * 10000.0f);
    float step = emaxp[0] / 7.0f;              // matches jnp.linspace step
    int cnt = 0;
    #pragma unroll
    for (int i = 0; i < 7; i++) cnt += (((float)i * step) < e) ? 1 : 0;  // searchsorted 'left'
    int tok = cnt > 6 ? 6 : cnt;
    src = temb + (long)tok * D_;
  }
  float4 o = *(const float4*)(src + lane*4);
  *(float4*)(x + (long)rowi*D_ + lane*4) = o;
}

// ---------------- LayerNorm: one wave per row, bf16 output ----------------
__global__ __launch_bounds__(256) void ln_k(const float* __restrict__ x,
    unsigned short* __restrict__ out,
    const float* __restrict__ g, const float* __restrict__ bb)
{
  int row = blockIdx.x*4 + (threadIdx.x >> 6);
  int lane = threadIdx.x & 63;
  float4 v = *(const float4*)(x + (long)row*D_ + lane*4);
  float s = v.x + v.y + v.z + v.w;
  float q = v.x*v.x + v.y*v.y + v.z*v.z + v.w*v.w;
  #pragma unroll
  for (int m = 1; m < 64; m <<= 1){ s += __shfl_xor(s, m); q += __shfl_xor(q, m); }
  float mu  = s * (1.0f/D_);
  float var = q * (1.0f/D_) - mu*mu;
  float inv = 1.0f / sqrtf(fmaxf(var, 0.f) + 1e-5f);
  float4 gu = *(const float4*)(g + lane*4);
  float4 bu = *(const float4*)(bb + lane*4);
  ushort4 o;
  o.x = f2us((v.x - mu)*inv*gu.x + bu.x);
  o.y = f2us((v.y - mu)*inv*gu.y + bu.y);
  o.z = f2us((v.z - mu)*inv*gu.z + bu.z);
  o.w = f2us((v.w - mu)*inv*gu.w + bu.w);
  *(ushort4*)(out + (long)row*D_ + lane*4) = o;
}

// ---------------- weight convert + transpose: dst[n][k] = bf16(src[k][n]) ----------------
__global__ __launch_bounds__(256) void wcvt_k(const float* __restrict__ src, long srcL,
    unsigned short* __restrict__ dst, long dstL, int K, int N)
{
  __shared__ float t[32][33];
  int n0 = blockIdx.x*32, k0 = blockIdx.y*32, L = blockIdx.z;
  int tx = threadIdx.x & 31, ty = threadIdx.x >> 5;
  const float* s = src + (long)L*srcL;
  for (int i = ty; i < 32; i += 8)
    t[i][tx] = s[(long)(k0+i)*N + n0 + tx];
  __syncthreads();
  unsigned short* d = dst + (long)L*dstL;
  for (int i = ty; i < 32; i += 8)
    d[(long)(n0 + i)*K + k0 + tx] = f2us(t[tx][i]);
}

// ---------------- proj convert + zero kmax slots ----------------
__global__ __launch_bounds__(256) void pcvt_k(const float* __restrict__ proj,
                                              unsigned short* __restrict__ projb,
                                              unsigned* __restrict__ kmaxb)
{
  int L = blockIdx.x;
  if (blockIdx.x == 0 && threadIdx.x < DEPTH_) kmaxb[threadIdx.x] = 0u;
  for (int i = threadIdx.x; i < 112*32; i += 256){
    int m = i >> 5, d = i & 31;
    float v = (m < M_) ? proj[(long)L*M_*DH + m*DH + d] : 0.f;
    projb[(long)L*112*32 + i] = f2us(v);
  }
}

// ---------------- bias concat: bqkv[L][768] = [bq|bk|bv] ----------------
__global__ __launch_bounds__(256) void bcat_k(const float* __restrict__ bq,
    const float* __restrict__ bk, const float* __restrict__ bv,
    float* __restrict__ bqkv)
{
  int L = blockIdx.x;
  for (int i = threadIdx.x; i < QS; i += 256){
    float v = (i < 256) ? bq[L*256 + i] : (i < 512) ? bk[L*256 + i - 256] : bv[L*256 + i - 512];
    bqkv[(long)L*QS + i] = v;
  }
}

// ---------------- bf16 MFMA GEMM: double-buffered LDS, one barrier per K-step ----------------
template<int ACT, int RES, int OUTBF>
__global__ __launch_bounds__(256) void bgemm_k(
    const unsigned short* __restrict__ A, long lda,
    const unsigned short* __restrict__ Bt,
    const float* __restrict__ bias,
    const float* __restrict__ res,
    float* __restrict__ Cf, unsigned short* __restrict__ Cb,
    int M, int Nn, int K)
{
  __shared__ __attribute__((aligned(16))) unsigned short smem[2*2*128*40];
  int tid = threadIdx.x;
  int colBlk = blockIdx.x*128, rowBlk = blockIdx.y*128;
  int w = tid >> 6, lane = tid & 63;
  int wrow = (w >> 1)*64, wcol = (w & 1)*64;
  int fr = lane & 15, fk = (lane >> 4)*8, fq = lane >> 4;
  int srh = tid >> 2, sk8 = (tid & 3)*8;

  f4v acc[4][4];
  #pragma unroll
  for (int r = 0; r < 4; r++)
    #pragma unroll
    for (int c = 0; c < 4; c++) acc[r][c] = (f4v){0.f, 0.f, 0.f, 0.f};

  s8v pa[2], pb[2];
  #pragma unroll
  for (int half = 0; half < 2; half++){
    int r = half*64 + srh;
    int ar = rowBlk + r;
    pa[half] = (ar < M) ? *(const s8v*)(A + (long)ar*lda + sk8) : (s8v){0,0,0,0,0,0,0,0};
    pb[half] = *(const s8v*)(Bt + (long)(colBlk + r)*K + sk8);
  }

  int it = 0;
  for (int kt = 0; kt < K; kt += 32, ++it){
    unsigned short* As = smem + (it & 1)*(2*128*40);
    unsigned short* Bs = As + 128*40;
    #pragma unroll
    for (int half = 0; half < 2; half++){
      int r = half*64 + srh;
      *(s8v*)&As[r*40 + sk8] = pa[half];
      *(s8v*)&Bs[r*40 + sk8] = pb[half];
    }
    __syncthreads();
    if (kt + 32 < K){
      int kn = kt + 32;
      #pragma unroll
      for (int half = 0; half < 2; half++){
        int r = half*64 + srh;
        int ar = rowBlk + r;
        pa[half] = (ar < M) ? *(const s8v*)(A + (long)ar*lda + kn + sk8) : (s8v){0,0,0,0,0,0,0,0};
        pb[half] = *(const s8v*)(Bt + (long)(colBlk + r)*K + kn + sk8);
      }
    }
    s8v a[4], b[4];
    #pragma unroll
    for (int r = 0; r < 4; r++) a[r] = *(s8v*)&As[(wrow + r*16 + fr)*40 + fk];
    #pragma unroll
    for (int c = 0; c < 4; c++) b[c] = *(s8v*)&Bs[(wcol + c*16 + fr)*40 + fk];
    #pragma unroll
    for (int r = 0; r < 4; r++)
      #pragma unroll
      for (int c = 0; c < 4; c++)
        acc[r][c] = __builtin_amdgcn_mfma_f32_16x16x32_bf16(a[r], b[c], acc[r][c], 0, 0, 0);
  }

  if (OUTBF){
    __syncthreads();
    unsigned short* Cs = smem;             // [128][132]
    #pragma unroll
    for (int c = 0; c < 4; c++){
      int col = wcol + c*16 + fr;
      float bz = bias[colBlk + col];
      #pragma unroll
      for (int r = 0; r < 4; r++){
        #pragma unroll
        for (int j = 0; j < 4; j++){
          int rrow = wrow + r*16 + fq*4 + j;
          float val = acc[r][c][j] + bz;
          if (ACT == 1) val = 0.5f * val * (1.0f + erff(val * 0.70710678118654752f));
          Cs[rrow*132 + col] = f2us(val);
        }
      }
    }
    __syncthreads();
    for (int ci = tid; ci < 128*16; ci += 256){
      int rrow = ci >> 4, ch = ci & 15;
      int grow = rowBlk + rrow;
      if (grow < M)
        *(s8v*)(Cb + (long)grow*Nn + colBlk + ch*8) = *(s8v*)&Cs[rrow*132 + ch*8];
    }
  } else {
    #pragma unroll
    for (int c = 0; c < 4; c++){
      int col = colBlk + wcol + c*16 + fr;
      float bz = bias[col];
      #pragma unroll
      for (int r = 0; r < 4; r++){
        #pragma unroll
        for (int j = 0; j < 4; j++){
          int row = rowBlk + wrow + r*16 + fq*4 + j;
          if (row < M){
            float val = acc[r][c][j] + bz;
            if (ACT == 1) val = 0.5f * val * (1.0f + erff(val * 0.70710678118654752f));
            if (RES) val += res[(long)row*Nn + col];
            Cf[(long)row*Nn + col] = val;
          }
        }
      }
    }
  }
}

// ---------------- fp32 GEMM (head only: 8 rows) ----------------
__global__ __launch_bounds__(256) void gemm_k(
    const float* __restrict__ A, long lda,
    const float* __restrict__ Bw, long ldb,
    const float* __restrict__ bias,
    float* __restrict__ Cf,
    int M, int Nn, int K)
{
  __shared__ float As[16][64];
  __shared__ float Bs[16][64];
  int tid = threadIdx.x;
  int tx = tid & 15, ty = tid >> 4;
  int rowBlk = blockIdx.x * 64, colBlk = blockIdx.y * 64;
  int am = tid >> 2, ak = (tid & 3) * 4;
  int bk = tid >> 4, bc = (tid & 15) * 4;
  float acc[4][4];
  #pragma unroll
  for (int i = 0; i < 4; i++)
    #pragma unroll
    for (int j = 0; j < 4; j++) acc[i][j] = 0.f;

  for (int kt = 0; kt < K; kt += 16){
    float4 av = make_float4(0.f, 0.f, 0.f, 0.f);
    int ar = rowBlk + am;
    if (ar < M) av = *(const float4*)(A + (long)ar*lda + kt + ak);
    As[ak+0][am] = av.x; As[ak+1][am] = av.y; As[ak+2][am] = av.z; As[ak+3][am] = av.w;
    float4 bv4 = *(const float4*)(Bw + (long)(kt + bk)*ldb + colBlk + bc);
    Bs[bk][bc+0] = bv4.x; Bs[bk][bc+1] = bv4.y;
    Bs[bk][bc+2] = bv4.z; Bs[bk][bc+3] = bv4.w;
    __syncthreads();
    #pragma unroll
    for (int kk = 0; kk < 16; kk++){
      float4 a4 = *(const float4*)&As[kk][ty*4];
      float4 b4 = *(const float4*)&Bs[kk][tx*4];
      acc[0][0] += a4.x*b4.x; acc[0][1] += a4.x*b4.y; acc[0][2] += a4.x*b4.z; acc[0][3] += a4.x*b4.w;
      acc[1][0] += a4.y*b4.x; acc[1][1] += a4.y*b4.y; acc[1][2] += a4.y*b4.z; acc[1][3] += a4.y*b4.w;
      acc[2][0] += a4.z*b4.x; acc[2][1] += a4.z*b4.y; acc[2][2] += a4.z*b4.z; acc[2][3] += a4.z*b4.w;
      acc[3][0] += a4.w*b4.x; acc[3][1] += a4.w*b4.y; acc[3][2] += a4.w*b4.z; acc[3][3] += a4.w*b4.w;
    }
    __syncthreads();
  }
  int r0 = rowBlk + ty*4, c0 = colBlk + tx*4;
  float bz[4];
  #pragma unroll
  for (int j = 0; j < 4; j++) bz[j] = bias[c0 + j];
  #pragma unroll
  for (int i = 0; i < 4; i++){
    int r = r0 + i;
    if (r < M){
      #pragma unroll
      for (int j = 0; j < 4; j++)
        Cf[(long)r*Nn + c0 + j] = acc[i][j] + bz[j];
    }
  }
}

// ---------------- kmax via MFMA (k slice of bf16 qkv) ----------------
__global__ __launch_bounds__(256) void kmax2_k(const unsigned short* __restrict__ qkvb,
    const unsigned short* __restrict__ projb, unsigned* __restrict__ kmaxb)
{
  __shared__ __attribute__((aligned(16))) unsigned short ks[64*40];
  __shared__ float red[4];
  int t = blockIdx.x, h = blockIdx.y, b = blockIdx.z;
  int tid = threadIdx.x, w = tid >> 6, lane = tid & 63;
  int fr = lane & 15, fq = lane >> 4, fk = fq*8;
  int n0 = t*64;
  {
    int tok = tid >> 2, d8 = (tid & 3)*8;
    int n = n0 + tok;
    bool vld = (n < N_);
    s8v kv8 = vld ? *(const s8v*)(qkvb + ((long)(b*N_ + n))*QS + 256 + h*DH + d8)
                  : (s8v){0,0,0,0,0,0,0,0};
    *(s8v*)&ks[tok*40 + d8] = kv8;
  }
  __syncthreads();
  s8v bk_ = *(s8v*)&ks[(w*16 + fr)*40 + fk];
  float mx = -INFINITY;
  int n_ = w*16 + fr;
  bool nv = (n0 + n_ < N_);
  #pragma unroll
  for (int mt = 0; mt < 7; mt++){
    s8v ap = *(const s8v*)(projb + (mt*16 + fr)*32 + fk);
    f4v z = (f4v){0.f,0.f,0.f,0.f};
    f4v xd = __builtin_amdgcn_mfma_f32_16x16x32_bf16(ap, bk_, z, 0, 0, 0);
    #pragma unroll
    for (int j = 0; j < 4; j++){
      int m = mt*16 + fq*4 + j;
      float v = (nv && m < M_) ? xd[j]*DN : -INFINITY;
      mx = fmaxf(mx, v);
    }
  }
  #pragma unroll
  for (int mk = 1; mk < 64; mk <<= 1) mx = fmaxf(mx, __shfl_xor(mx, mk));
  if (lane == 0) red[w] = mx;
  __syncthreads();
  if (tid == 0){
    float g = fmaxf(fmaxf(red[0], red[1]), fmaxf(red[2], red[3]));
    atomicMax(kmaxb, floatToOrdered(g));
  }
}

// ---------------- fused ctx via double MFMA (bf16 qkv) ----------------
__global__ __launch_bounds__(256) void fctx_k(const unsigned short* __restrict__ qkvb,
    const unsigned short* __restrict__ projb,
    const unsigned* __restrict__ kmaxb, float* __restrict__ partials)
{
  __shared__ __attribute__((aligned(16))) unsigned short ks[64*40];
  __shared__ __attribute__((aligned(16))) unsigned short vt[48*72];
  __shared__ __attribute__((aligned(16))) unsigned short kps[112*72];
  __shared__ float diags[64];
  int c = blockIdx.x, h = blockIdx.y, b = blockIdx.z;
  int tid = threadIdx.x, w = tid >> 6, lane = tid & 63;
  int fr = lane & 15, fq = lane >> 4, fk = fq*8;
  float kmax = orderedToFloat(kmaxb[0]);

  for (int i = tid; i < 15*72; i += 256) vt[33*72 + i] = 0;
  if (tid < 64) vt[32*72 + tid] = f2us(1.0f);

  s8v ap[7];
  #pragma unroll
  for (int mt = 0; mt < 7; mt++)
    ap[mt] = *(const s8v*)(projb + (mt*16 + fr)*32 + fk);

  int mt0 = w, mt1 = w + 4;
  f4v acc0[3], acc1[3];
  #pragma unroll
  for (int dt = 0; dt < 3; dt++){ acc0[dt] = (f4v){0.f,0.f,0.f,0.f}; acc1[dt] = (f4v){0.f,0.f,0.f,0.f}; }

  int stok = tid >> 2, sd8 = (tid & 3)*8;
  for (int t = c; t < NTILES; t += NC){
    int n0 = t*64;
    __syncthreads();
    {
      int n = n0 + stok;
      bool vld = (n < N_);
      long gb = ((long)(b*N_ + (vld ? n : 0)))*QS + h*DH + sd8;
      s8v kv8 = vld ? *(const s8v*)(qkvb + gb + 256) : (s8v){0,0,0,0,0,0,0,0};
      s8v vv8 = vld ? *(const s8v*)(qkvb + gb + 512) : (s8v){0,0,0,0,0,0,0,0};
      *(s8v*)&ks[stok*40 + sd8] = kv8;
      #pragma unroll
      for (int j = 0; j < 8; j++)
        vt[(sd8 + j)*72 + stok] = (unsigned short)vv8[j];
      float sq = 0.f;
      #pragma unroll
      for (int j = 0; j < 8; j++){
        float kx = us2f((unsigned short)kv8[j]);
        sq += kx*kx;
      }
      sq += __shfl_xor(sq, 1); sq += __shfl_xor(sq, 2);
      if ((tid & 3) == 0) diags[stok] = 0.5f * DN2 * sq;
    }
    __syncthreads();
    s8v bk_ = *(s8v*)&ks[(w*16 + fr)*40 + fk];
    int n_ = w*16 + fr;
    bool nv = (n0 + n_ < N_);
    float dgn = diags[n_];
    #pragma unroll
    for (int mt = 0; mt < 7; mt++){
      f4v z = (f4v){0.f,0.f,0.f,0.f};
      f4v xd = __builtin_amdgcn_mfma_f32_16x16x32_bf16(ap[mt], bk_, z, 0, 0, 0);
      #pragma unroll
      for (int j = 0; j < 4; j++){
        float kp = nv ? RATIO*(expf(xd[j]*DN - dgn - kmax) + 1e-3f) : 0.f;
        kps[(mt*16 + fq*4 + j)*72 + n_] = f2us(kp);
      }
    }
    __syncthreads();
    #pragma unroll
    for (int kst = 0; kst < 2; kst++){
      int ko = kst*32 + fk;
      s8v b0 = *(s8v*)&vt[( 0 + fr)*72 + ko];
      s8v b1 = *(s8v*)&vt[(16 + fr)*72 + ko];
      s8v b2 = *(s8v*)&vt[(32 + fr)*72 + ko];
      s8v a0 = *(s8v*)&kps[(mt0*16 + fr)*72 + ko];
      acc0[0] = __builtin_amdgcn_mfma_f32_16x16x32_bf16(a0, b0, acc0[0], 0, 0, 0);
      acc0[1] = __builtin_amdgcn_mfma_f32_16x16x32_bf16(a0, b1, acc0[1], 0, 0, 0);
      acc0[2] = __builtin_amdgcn_mfma_f32_16x16x32_bf16(a0, b2, acc0[2], 0, 0, 0);
      if (mt1 < 7){
        s8v a1 = *(s8v*)&kps[(mt1*16 + fr)*72 + ko];
        acc1[0] = __builtin_amdgcn_mfma_f32_16x16x32_bf16(a1, b0, acc1[0], 0, 0, 0);
        acc1[1] = __builtin_amdgcn_mfma_f32_16x16x32_bf16(a1, b1, acc1[1], 0, 0, 0);
        acc1[2] = __builtin_amdgcn_mfma_f32_16x16x32_bf16(a1, b2, acc1[2], 0, 0, 0);
      }
    }
  }
  long pb = ((long)c*64 + (b*H_ + h))*CTXE;
  #pragma unroll
  for (int dt = 0; dt < 3; dt++){
    int d = dt*16 + fr;
    if (d < 33){
      #pragma unroll
      for (int j = 0; j < 4; j++){
        int m0 = mt0*16 + fq*4 + j;
        if (m0 < M_) partials[pb + m0*33 + d] = acc0[dt][j];
        if (mt1 < 7){
          int m1 = mt1*16 + fq*4 + j;
          if (m1 < M_) partials[pb + m1*33 + d] = acc1[dt][j];
        }
      }
    }
  }
}

// ---------------- ctx partial reduce (coalesced; restored from round 15) ----------------
__global__ __launch_bounds__(256) void ctxred2_k(const float* __restrict__ partials,
                                                 float* __restrict__ ctxf)
{
  int i = blockIdx.x*256 + threadIdx.x;
  if (i >= CTXN2) return;
  float s = 0.f;
  #pragma unroll
  for (int c = 0; c < NC; c++) s += partials[(long)c*CTXN2 + i];
  ctxf[i] = s;
}

// ---------------- attn v3: full-MFMA query side (bf16 qkv; reads reduced ctxf) ----------------
__global__ __launch_bounds__(256) void attn3_k(const unsigned short* __restrict__ qkvb,
    const float* __restrict__ ctxf, const unsigned short* __restrict__ projb,
    unsigned short* __restrict__ ob)
{
  __shared__ __attribute__((aligned(16))) unsigned short qs[64*40];
  __shared__ __attribute__((aligned(16))) unsigned short qps[64*136];
  __shared__ __attribute__((aligned(16))) unsigned short cst[48*136];
  __shared__ float diags[64];
  __shared__ float dens[64];
  int t = blockIdx.x, h = blockIdx.y, b = blockIdx.z;
  int tid = threadIdx.x, w = tid >> 6, lane = tid & 63;
  int fr = lane & 15, fq = lane >> 4, fk = fq*8;
  int n0 = t*64;
  long cbase = ((long)(b*H_ + h))*CTXE;

  for (int i = tid; i < 64*16; i += 256)
    qps[(i >> 4)*136 + 112 + (i & 15)] = 0;

  {
    int tok = tid >> 2, d8 = (tid & 3)*8;
    int n = n0 + tok;
    bool vld = (n < N_);
    s8v qv8 = vld ? *(const s8v*)(qkvb + ((long)(b*N_ + n))*QS + h*DH + d8)
                  : (s8v){0,0,0,0,0,0,0,0};
    *(s8v*)&qs[tok*40 + d8] = qv8;
    float sq = 0.f;
    #pragma unroll
    for (int j = 0; j < 8; j++){
      float qx = us2f((unsigned short)qv8[j]);
      sq += qx*qx;
    }
    sq += __shfl_xor(sq, 1); sq += __shfl_xor(sq, 2);
    if ((tid & 3) == 0) diags[tok] = 0.5f * DN2 * sq;
  }
  for (int i = tid; i < 48*128; i += 256){
    int d = i >> 7, m = i & 127;
    float v = (d < 33 && m < M_) ? ctxf[cbase + (long)m*33 + d] : 0.f;
    cst[d*136 + m] = f2us(v);
  }
  __syncthreads();

  s8v bq_ = *(s8v*)&qs[(w*16 + fr)*40 + fk];
  int n_ = w*16 + fr;
  bool nv = (n0 + n_ < N_);
  float dgn = diags[n_];
  f4v xdv[7];
  #pragma unroll
  for (int mt = 0; mt < 7; mt++){
    s8v ap = *(const s8v*)(projb + (mt*16 + fr)*32 + fk);
    f4v z = (f4v){0.f,0.f,0.f,0.f};
    xdv[mt] = __builtin_amdgcn_mfma_f32_16x16x32_bf16(ap, bq_, z, 0, 0, 0);
  }
  float mx = -INFINITY;
  #pragma unroll
  for (int mt = 0; mt < 7; mt++)
    #pragma unroll
    for (int j = 0; j < 4; j++){
      int m = mt*16 + fq*4 + j;
      if (m < M_) mx = fmaxf(mx, xdv[mt][j]*DN);
    }
  mx = fmaxf(mx, __shfl_xor(mx, 16));
  mx = fmaxf(mx, __shfl_xor(mx, 32));
  #pragma unroll
  for (int mt = 0; mt < 7; mt++)
    #pragma unroll
    for (int j = 0; j < 4; j++){
      int m = mt*16 + fq*4 + j;
      float qp = (nv && m < M_) ? RATIO*(expf(xdv[mt][j]*DN - dgn - mx) + 1e-3f) : 0.f;
      qps[n_*136 + m] = f2us(qp);
    }
  __syncthreads();

  f4v acc[3];
  acc[0] = (f4v){0,0,0,0}; acc[1] = (f4v){0,0,0,0}; acc[2] = (f4v){0,0,0,0};
  #pragma unroll
  for (int ks = 0; ks < 4; ks++){
    int ko = ks*32 + fk;
    s8v bqp = *(s8v*)&qps[(w*16 + fr)*136 + ko];
    #pragma unroll
    for (int dt = 0; dt < 3; dt++){
      s8v ac = *(s8v*)&cst[(dt*16 + fr)*136 + ko];
      acc[dt] = __builtin_amdgcn_mfma_f32_16x16x32_bf16(ac, bqp, acc[dt], 0, 0, 0);
    }
  }
  if (fq == 0) dens[n_] = acc[2][0];
  __syncthreads();
  float dinv = 1.0f / dens[n_];
  if (nv){
    long obase = ((long)(b*N_ + n0 + n_))*D_ + h*DH;
    #pragma unroll
    for (int dt = 0; dt < 2; dt++){
      ushort4 wv;
      wv.x = f2us(acc[dt][0]*dinv);
      wv.y = f2us(acc[dt][1]*dinv);
      wv.z = f2us(acc[dt][2]*dinv);
      wv.w = f2us(acc[dt][3]*dinv);
      *(ushort4*)(ob + obase + dt*16 + fq*4) = wv;
    }
  }
}

// ---------------- host ----------------
extern "C" void kernel_launch(void* const* d_in, const int* in_sizes, int n_in,
                              void* d_out, int out_size, void* d_ws, size_t ws_size,
                              hipStream_t stream)
{
  const float* expr = (const float*)d_in[0];
  const float* temb = (const float*)d_in[1];
  const float* cls  = (const float*)d_in[2];
  const float* ln1g = (const float*)d_in[3];
  const float* ln1b = (const float*)d_in[4];
  const float* Wq   = (const float*)d_in[5];
  const float* bq   = (const float*)d_in[6];
  const float* Wk   = (const float*)d_in[7];
  const float* bk   = (const float*)d_in[8];
  const float* Wv   = (const float*)d_in[9];
  const float* bv   = (const float*)d_in[10];
  const float* Wo   = (const float*)d_in[11];
  const float* bo   = (const float*)d_in[12];
  const float* ln2g = (const float*)d_in[13];
  const float* ln2b = (const float*)d_in[14];
  const float* W1   = (const float*)d_in[15];
  const float* b1   = (const float*)d_in[16];
  const float* W2   = (const float*)d_in[17];
  const float* b2   = (const float*)d_in[18];
  const float* proj = (const float*)d_in[19];
  const float* Wp   = (const float*)d_in[20];
  const float* bp   = (const float*)d_in[21];
  (void)in_sizes; (void)n_in; (void)out_size; (void)ws_size;

  char* w = (char*)d_ws;
  size_t off = 0;
  auto alloc = [&](size_t bytes) -> char* {
    char* p = w + off;
    off = (off + bytes + 255) & ~(size_t)255;
    return p;
  };
  float*    selected = (float*)alloc((size_t)B_*KSEL*4);
  float*    bsum     = (float*)alloc(B_*4);
  float*    bv0      = (float*)alloc(B_*4);
  float*    emaxp    = (float*)alloc(4);
  unsigned* kmaxb    = (unsigned*)alloc(DEPTH_*4);
  float*    ctxf     = (float*)alloc((size_t)CTXN2*4);
  float*          x  = (float*)alloc((size_t)BN_*D_*4);
  unsigned short* h  = (unsigned short*)alloc((size_t)BN_*D_*2);
  unsigned short* qkvb = (unsigned short*)alloc((size_t)BN_*DFF_*2);  // qkv bf16 (stride QS); ffi aliases (stride 1024)
  float*     partials = (float*)alloc((size_t)NC*CTXN2*4);
  unsigned short* Wqkvt = (unsigned short*)alloc((size_t)DEPTH_*QS*D_*2);
  unsigned short* Wot = (unsigned short*)alloc((size_t)DEPTH_*D_*D_*2);
  unsigned short* W1t = (unsigned short*)alloc((size_t)DEPTH_*D_*DFF_*2);
  unsigned short* W2t = (unsigned short*)alloc((size_t)DEPTH_*DFF_*D_*2);
  unsigned short* projb = (unsigned short*)alloc((size_t)DEPTH_*112*32*2);
  float*    bqkv     = (float*)alloc((size_t)DEPTH_*QS*4);
  unsigned short* ffi = qkvb;                  // bf16 [BN][1024] aliases qkv (dead during FFN)

  wcvt_k<<<dim3(8, 8, DEPTH_),  256, 0, stream>>>(Wq, (long)D_*D_, Wqkvt + 0,      (long)QS*D_, D_, D_);
  wcvt_k<<<dim3(8, 8, DEPTH_),  256, 0, stream>>>(Wk, (long)D_*D_, Wqkvt + 256*D_, (long)QS*D_, D_, D_);
  wcvt_k<<<dim3(8, 8, DEPTH_),  256, 0, stream>>>(Wv, (long)D_*D_, Wqkvt + 512*D_, (long)QS*D_, D_, D_);
  wcvt_k<<<dim3(8, 8, DEPTH_),  256, 0, stream>>>(Wo, (long)D_*D_,   Wot, (long)D_*D_,   D_, D_);
  wcvt_k<<<dim3(32, 8, DEPTH_), 256, 0, stream>>>(W1, (long)D_*DFF_, W1t, (long)D_*DFF_, D_, DFF_);
  wcvt_k<<<dim3(8, 32, DEPTH_), 256, 0, stream>>>(W2, (long)DFF_*D_, W2t, (long)DFF_*D_, DFF_, D_);
  pcvt_k<<<DEPTH_, 256, 0, stream>>>(proj, projb, kmaxb);
  bcat_k<<<DEPTH_, 256, 0, stream>>>(bq, bk, bv, bqkv);

  topk_k<<<B_, 1024, 0, stream>>>(expr, selected, bsum, bv0);
  emax_k<<<1, 64, 0, stream>>>(bsum, bv0, emaxp);
  embed_k<<<BN_/4, 256, 0, stream>>>(selected, bsum, emaxp, temb, cls, x);

  for (int L = 0; L < DEPTH_; L++){
    const unsigned short* pjb = projb + (size_t)L*112*32;
    ln_k<<<BN_/4, 256, 0, stream>>>(x, h, ln1g + L*D_, ln1b + L*D_);
    bgemm_k<0,0,1><<<dim3(6,129), 256, 0, stream>>>(h, D_, Wqkvt + (size_t)L*QS*D_, bqkv + (size_t)L*QS, nullptr, nullptr, qkvb, BN_, QS, D_);
    kmax2_k<<<dim3(NTILES, H_, B_), 256, 0, stream>>>(qkvb, pjb, kmaxb + L);
    fctx_k<<<dim3(NC, H_, B_), 256, 0, stream>>>(qkvb, pjb, kmaxb + L, partials);
    ctxred2_k<<<(CTXN2 + 255)/256, 256, 0, stream>>>(partials, ctxf);
    attn3_k<<<dim3(NTILES, H_, B_), 256, 0, stream>>>(qkvb, ctxf, pjb, h);   // o -> h (bf16)
    bgemm_k<0,1,0><<<dim3(2,129), 256, 0, stream>>>(h, D_, Wot + (size_t)L*D_*D_, bo + L*D_, x, x, nullptr, BN_, D_, D_);
    ln_k<<<BN_/4, 256, 0, stream>>>(x, h, ln2g + L*D_, ln2b + L*D_);
    bgemm_k<1,0,1><<<dim3(8,129), 256, 0, stream>>>(h, D_, W1t + (size_t)L*D_*DFF_, b1 + L*DFF_, nullptr, nullptr, ffi, BN_, DFF_, D_);
    bgemm_k<0,1,0><<<dim3(2,129), 256, 0, stream>>>(ffi, DFF_, W2t + (size_t)L*DFF_*D_, b2 + L*D_, x, x, nullptr, BN_, D_, DFF_);
  }
  gemm_k<<<dim3(1,4), 256, 0, stream>>>(x, (long)N_*D_, Wp, D_, bp,
                                        (float*)d_out, B_, D_, D_);
}

// Round 18
// 1308.758 us; speedup vs baseline: 1.9631x; 1.0139x over previous
//
#include <hip/hip_runtime.h>
#include <hip/hip_bf16.h>

#define B_    8
#define NG    16906
#define KSEL  2048
#define D_    256
#define H_    8
#define DH    32
#define M_    110
#define DEPTH_ 6
#define DFF_  1024
#define N_    2049
#define BN_   (B_*N_)
#define QS    768          // fused qkv row stride (shorts)
#define NC    8            // fctx chunks (blocks per (b,h))
#define NTILES 33          // ceil(2049/64)
#define CTXE  (M_*33)      // 3630 per (b,h)
#define CTXN2 (64*CTXE)    // 232320
#define NIT_TK 17          // ceil(16906/1024)

static constexpr float DN    = 0.42044820762685725f;  // 32^-0.25
static constexpr float DN2   = 0.17677669529663687f;  // 32^-0.5
static constexpr float RATIO = 0.09534625892455922f;  // 110^-0.5

typedef __attribute__((ext_vector_type(8))) short s8v;
typedef __attribute__((ext_vector_type(4))) float f4v;

__device__ __forceinline__ unsigned floatToOrdered(float f){
  unsigned b = __float_as_uint(f);
  return (b & 0x80000000u) ? ~b : (b | 0x80000000u);
}
__device__ __forceinline__ float orderedToFloat(unsigned u){
  unsigned b = (u & 0x80000000u) ? (u & 0x7FFFFFFFu) : ~u;
  return __uint_as_float(b);
}
__device__ __forceinline__ unsigned short f2us(float f){
  __hip_bfloat16 b = __float2bfloat16(f);
  return *reinterpret_cast<unsigned short*>(&b);
}
__device__ __forceinline__ float us2f(unsigned short u){
  return __uint_as_float(((unsigned)u) << 16);
}

// ---------------- top-k: radix select + fused per-batch sum/max ----------------
__global__ __launch_bounds__(1024) void topk_k(const float* __restrict__ expr,
                                               float* __restrict__ selected,
                                               float* __restrict__ bsum,
                                               float* __restrict__ bv0)
{
  __shared__ unsigned histw[16*256];
  __shared__ unsigned sPrefix;
  __shared__ int sKK;
  __shared__ unsigned cGT, cEQ;
  int b = blockIdx.x, tid = threadIdx.x;
  int wv = tid >> 6, lane = tid & 63;
  const float* row = expr + (long)b*NG;
  unsigned rb[NIT_TK];
  #pragma unroll
  for (int i = 0; i < NIT_TK; i++){
    int idx = tid + i*1024;
    rb[i] = (idx < NG) ? __float_as_uint(row[idx]) : 0u;
  }
  if (tid == 0){ sPrefix = 0u; sKK = KSEL; }
  for (int pass = 0; pass < 4; ++pass){
    int shift = 24 - pass*8;
    for (int i = tid; i < 16*256; i += 1024) histw[i] = 0u;
    __syncthreads();
    unsigned pref = sPrefix;
    unsigned kk  = (unsigned)sKK;
    #pragma unroll
    for (int i = 0; i < NIT_TK; i++){
      int idx = tid + i*1024;
      unsigned bits = rb[i];
      bool ok = (idx < NG) && ((pass == 0) || ((bits >> (shift + 8)) == pref));
      if (ok) atomicAdd(&histw[wv*256 + ((bits >> shift) & 255u)], 1u);
    }
    __syncthreads();
    if (tid < 256){
      unsigned s = 0;
      #pragma unroll
      for (int w = 0; w < 16; w++) s += histw[w*256 + tid];
      histw[tid] = s;
    }
    __syncthreads();
    unsigned* bufA = histw;
    unsigned* bufB = histw + 256;
    for (int d = 1; d < 256; d <<= 1){
      if (tid < 256)
        bufB[tid] = bufA[tid] + ((tid + d < 256) ? bufA[tid + d] : 0u);
      __syncthreads();
      unsigned* t = bufA; bufA = bufB; bufB = t;
    }
    if (tid < 256){
      unsigned sj  = bufA[tid];
      unsigned sj1 = (tid < 255) ? bufA[tid + 1] : 0u;
      if (sj >= kk && sj1 < kk){
        sPrefix = (pref << 8) | (unsigned)tid;
        sKK = (int)(kk - sj1);
      }
    }
    __syncthreads();
  }
  unsigned T = sPrefix; int needEQ = sKK; int base = KSEL - needEQ;
  if (tid == 0){ cGT = 0u; cEQ = 0u; }
  __syncthreads();
  #pragma unroll
  for (int i = 0; i < NIT_TK; i++){
    int idx = tid + i*1024;
    bool v = (idx < NG);
    unsigned bits = rb[i];
    bool gt = v && (bits > T);
    unsigned long long mgt = __ballot(gt);
    if (mgt){
      int leader = __ffsll((long long)mgt) - 1;
      unsigned wbase = 0;
      if (lane == leader) wbase = atomicAdd(&cGT, (unsigned)__popcll(mgt));
      wbase = __shfl(wbase, leader);
      if (gt){
        int pre = __popcll(mgt & ((1ULL << lane) - 1ULL));
        selected[(long)b*KSEL + wbase + pre] = __uint_as_float(bits);
      }
    }
    bool eq = v && (bits == T);
    unsigned long long meq = __ballot(eq);
    if (meq){
      int leader = __ffsll((long long)meq) - 1;
      unsigned wbase = 0;
      if (lane == leader) wbase = atomicAdd(&cEQ, (unsigned)__popcll(meq));
      wbase = __shfl(wbase, leader);
      if (eq){
        int pos = (int)wbase + __popcll(meq & ((1ULL << lane) - 1ULL));
        if (pos < needEQ) selected[(long)b*KSEL + base + pos] = __uint_as_float(bits);
      }
    }
  }
  // fused per-batch sum & max (replaces nsum_k): sum = sum(>T) + needEQ*T; max = row max
  float gsum = 0.f; unsigned gmax = 0u;
  #pragma unroll
  for (int i = 0; i < NIT_TK; i++){
    int idx = tid + i*1024;
    if (idx < NG){
      unsigned bits = rb[i];
      if (bits > T) gsum += __uint_as_float(bits);
      gmax = max(gmax, bits);
    }
  }
  __syncthreads();
  float*    fs = (float*)histw;
  unsigned* um = histw + 1024;
  fs[tid] = gsum;
  um[tid] = gmax;
  __syncthreads();
  for (int k2 = 512; k2 > 0; k2 >>= 1){
    if (tid < k2){
      fs[tid] += fs[tid + k2];
      um[tid] = max(um[tid], um[tid + k2]);
    }
    __syncthreads();
  }
  if (tid == 0){
    bsum[b] = fs[0] + (float)needEQ * __uint_as_float(T);
    bv0[b]  = __uint_as_float(um[0]);
  }
}

// ---------------- global max of e = log1p(v0/sum*1e4) ----------------
__global__ __launch_bounds__(64) void emax_k(const float* __restrict__ bsum,
                                             const float* __restrict__ bv0,
                                             float* __restrict__ emaxp)
{
  int tid = threadIdx.x;
  float e = -INFINITY;
  if (tid < B_) e = log1pf(bv0[tid] / fmaxf(bsum[tid], 1e-12f) * 10000.0f);
  #pragma unroll
  for (int m = 1; m < 64; m <<= 1) e = fmaxf(e, __shfl_xor(e, m));
  if (tid == 0) emaxp[0] = e;
}

// ---------------- tokenize + embed: 4 rows per block ----------------
__global__ __launch_bounds__(256) void embed_k(const float* __restrict__ selected,
    const float* __restrict__ bsum, const float* __restrict__ emaxp,
    const float* __restrict__ temb, const float* __restrict__ cls,
    float* __restrict__ x)
{
  int rowi = blockIdx.x*4 + (threadIdx.x >> 6);
  int b = rowi / N_, n = rowi % N_;
  int lane = threadIdx.x & 63;
  const float* src;
  if (n == 0){
    src = cls;
  } else {
    float val = selected[(long)b*KSEL + (n - 1)];
    float e = log1pf(val / fmaxf(bsum[b], 1e-12f) * 10000.0f);
    float step = emaxp[0] / 7.0f;              // matches jnp.linspace step
    int cnt = 0;
    #pragma unroll
    for (int i = 0; i < 7; i++) cnt += (((float)i * step) < e) ? 1 : 0;  // searchsorted 'left'
    int tok = cnt > 6 ? 6 : cnt;
    src = temb + (long)tok * D_;
  }
  float4 o = *(const float4*)(src + lane*4);
  *(float4*)(x + (long)rowi*D_ + lane*4) = o;
}

// ---------------- LayerNorm: one wave per row, bf16 output ----------------
__global__ __launch_bounds__(256) void ln_k(const float* __restrict__ x,
    unsigned short* __restrict__ out,
    const float* __restrict__ g, const float* __restrict__ bb)
{
  int row = blockIdx.x*4 + (threadIdx.x >> 6);
  int lane = threadIdx.x & 63;
  float4 v = *(const float4*)(x + (long)row*D_ + lane*4);
  float s = v.x + v.y + v.z + v.w;
  float q = v.x*v.x + v.y*v.y + v.z*v.z + v.w*v.w;
  #pragma unroll
  for (int m = 1; m < 64; m <<= 1){ s += __shfl_xor(s, m); q += __shfl_xor(q, m); }
  float mu  = s * (1.0f/D_);
  float var = q * (1.0f/D_) - mu*mu;
  float inv = 1.0f / sqrtf(fmaxf(var, 0.f) + 1e-5f);
  float4 gu = *(const float4*)(g + lane*4);
  float4 bu = *(const float4*)(bb + lane*4);
  ushort4 o;
  o.x = f2us((v.x - mu)*inv*gu.x + bu.x);
  o.y = f2us((v.y - mu)*inv*gu.y + bu.y);
  o.z = f2us((v.z - mu)*inv*gu.z + bu.z);
  o.w = f2us((v.w - mu)*inv*gu.w + bu.w);
  *(ushort4*)(out + (long)row*D_ + lane*4) = o;
}

// ---------------- prep: ALL weight conversions in one dispatch ----------------
// blocks [0,1536): Wq/Wk/Wv/Wo (64 tiles/L each); [1536,3072): W1; [3072,4608): W2;
// [4608,4614): proj convert (+kmax zero); [4614,4620): bias concat.
__global__ __launch_bounds__(256) void prep_k(
    const float* __restrict__ Wq, const float* __restrict__ Wk,
    const float* __restrict__ Wv, const float* __restrict__ Wo,
    const float* __restrict__ W1, const float* __restrict__ W2,
    unsigned short* __restrict__ Wqkvt, unsigned short* __restrict__ Wot,
    unsigned short* __restrict__ W1t, unsigned short* __restrict__ W2t,
    const float* __restrict__ proj, unsigned short* __restrict__ projb,
    unsigned* __restrict__ kmaxb,
    const float* __restrict__ bq, const float* __restrict__ bk,
    const float* __restrict__ bv, float* __restrict__ bqkv)
{
  __shared__ float t[32][33];
  int bid = blockIdx.x;
  if (bid < 4608){
    const float* src; unsigned short* dst; long srcL, dstL; int K, N, L, tn, tk;
    if (bid < 1536){
      int job = bid / 384;
      int r = bid % 384; L = r / 64; int t2 = r % 64; tn = t2 % 8; tk = t2 / 8;
      K = D_; N = D_; srcL = (long)D_*D_;
      if (job == 0){ src = Wq; dst = Wqkvt;          dstL = (long)QS*D_; }
      else if (job == 1){ src = Wk; dst = Wqkvt + 256*D_; dstL = (long)QS*D_; }
      else if (job == 2){ src = Wv; dst = Wqkvt + 512*D_; dstL = (long)QS*D_; }
      else { src = Wo; dst = Wot; dstL = (long)D_*D_; }
    } else if (bid < 3072){
      int r = bid - 1536; L = r / 256; int t2 = r % 256; tn = t2 % 32; tk = t2 / 32;
      K = D_; N = DFF_; src = W1; dst = W1t; srcL = (long)D_*DFF_; dstL = (long)D_*DFF_;
    } else {
      int r = bid - 3072; L = r / 256; int t2 = r % 256; tn = t2 % 8; tk = t2 / 8;
      K = DFF_; N = D_; src = W2; dst = W2t; srcL = (long)DFF_*D_; dstL = (long)DFF_*D_;
    }
    int n0 = tn*32, k0 = tk*32;
    int tx = threadIdx.x & 31, ty = threadIdx.x >> 5;
    const float* s = src + (long)L*srcL;
    for (int i = ty; i < 32; i += 8)
      t[i][tx] = s[(long)(k0+i)*N + n0 + tx];
    __syncthreads();
    unsigned short* dd = dst + (long)L*dstL;
    for (int i = ty; i < 32; i += 8)
      dd[(long)(n0 + i)*K + k0 + tx] = f2us(t[tx][i]);
  } else if (bid < 4614){
    int L = bid - 4608;
    if (L == 0 && threadIdx.x < DEPTH_) kmaxb[threadIdx.x] = 0u;
    for (int i = threadIdx.x; i < 112*32; i += 256){
      int m = i >> 5, d = i & 31;
      float v = (m < M_) ? proj[(long)L*M_*DH + m*DH + d] : 0.f;
      projb[(long)L*112*32 + i] = f2us(v);
    }
  } else {
    int L = bid - 4614;
    for (int i = threadIdx.x; i < QS; i += 256){
      float v = (i < 256) ? bq[L*256 + i] : (i < 512) ? bk[L*256 + i - 256] : bv[L*256 + i - 512];
      bqkv[(long)L*QS + i] = v;
    }
  }
}

// ---------------- bf16 MFMA GEMM: double-buffered LDS, one barrier per K-step ----------------
template<int ACT, int RES, int OUTBF>
__global__ __launch_bounds__(256) void bgemm_k(
    const unsigned short* __restrict__ A, long lda,
    const unsigned short* __restrict__ Bt,
    const float* __restrict__ bias,
    const float* __restrict__ res,
    float* __restrict__ Cf, unsigned short* __restrict__ Cb,
    int M, int Nn, int K)
{
  __shared__ __attribute__((aligned(16))) unsigned short smem[2*2*128*40];
  int tid = threadIdx.x;
  int colBlk = blockIdx.x*128, rowBlk = blockIdx.y*128;
  int w = tid >> 6, lane = tid & 63;
  int wrow = (w >> 1)*64, wcol = (w & 1)*64;
  int fr = lane & 15, fk = (lane >> 4)*8, fq = lane >> 4;
  int srh = tid >> 2, sk8 = (tid & 3)*8;

  f4v acc[4][4];
  #pragma unroll
  for (int r = 0; r < 4; r++)
    #pragma unroll
    for (int c = 0; c < 4; c++) acc[r][c] = (f4v){0.f, 0.f, 0.f, 0.f};

  s8v pa[2], pb[2];
  #pragma unroll
  for (int half = 0; half < 2; half++){
    int r = half*64 + srh;
    int ar = rowBlk + r;
    pa[half] = (ar < M) ? *(const s8v*)(A + (long)ar*lda + sk8) : (s8v){0,0,0,0,0,0,0,0};
    pb[half] = *(const s8v*)(Bt + (long)(colBlk + r)*K + sk8);
  }

  int it = 0;
  for (int kt = 0; kt < K; kt += 32, ++it){
    unsigned short* As = smem + (it & 1)*(2*128*40);
    unsigned short* Bs = As + 128*40;
    #pragma unroll
    for (int half = 0; half < 2; half++){
      int r = half*64 + srh;
      *(s8v*)&As[r*40 + sk8] = pa[half];
      *(s8v*)&Bs[r*40 + sk8] = pb[half];
    }
    __syncthreads();
    if (kt + 32 < K){
      int kn = kt + 32;
      #pragma unroll
      for (int half = 0; half < 2; half++){
        int r = half*64 + srh;
        int ar = rowBlk + r;
        pa[half] = (ar < M) ? *(const s8v*)(A + (long)ar*lda + kn + sk8) : (s8v){0,0,0,0,0,0,0,0};
        pb[half] = *(const s8v*)(Bt + (long)(colBlk + r)*K + kn + sk8);
      }
    }
    s8v a[4], b[4];
    #pragma unroll
    for (int r = 0; r < 4; r++) a[r] = *(s8v*)&As[(wrow + r*16 + fr)*40 + fk];
    #pragma unroll
    for (int c = 0; c < 4; c++) b[c] = *(s8v*)&Bs[(wcol + c*16 + fr)*40 + fk];
    #pragma unroll
    for (int r = 0; r < 4; r++)
      #pragma unroll
      for (int c = 0; c < 4; c++)
        acc[r][c] = __builtin_amdgcn_mfma_f32_16x16x32_bf16(a[r], b[c], acc[r][c], 0, 0, 0);
  }

  if (OUTBF){
    __syncthreads();
    unsigned short* Cs = smem;             // [128][132]
    #pragma unroll
    for (int c = 0; c < 4; c++){
      int col = wcol + c*16 + fr;
      float bz = bias[colBlk + col];
      #pragma unroll
      for (int r = 0; r < 4; r++){
        #pragma unroll
        for (int j = 0; j < 4; j++){
          int rrow = wrow + r*16 + fq*4 + j;
          float val = acc[r][c][j] + bz;
          if (ACT == 1) val = 0.5f * val * (1.0f + erff(val * 0.70710678118654752f));
          Cs[rrow*132 + col] = f2us(val);
        }
      }
    }
    __syncthreads();
    for (int ci = tid; ci < 128*16; ci += 256){
      int rrow = ci >> 4, ch = ci & 15;
      int grow = rowBlk + rrow;
      if (grow < M)
        *(s8v*)(Cb + (long)grow*Nn + colBlk + ch*8) = *(s8v*)&Cs[rrow*132 + ch*8];
    }
  } else {
    #pragma unroll
    for (int c = 0; c < 4; c++){
      int col = colBlk + wcol + c*16 + fr;
      float bz = bias[col];
      #pragma unroll
      for (int r = 0; r < 4; r++){
        #pragma unroll
        for (int j = 0; j < 4; j++){
          int row = rowBlk + wrow + r*16 + fq*4 + j;
          if (row < M){
            float val = acc[r][c][j] + bz;
            if (ACT == 1) val = 0.5f * val * (1.0f + erff(val * 0.70710678118654752f));
            if (RES) val += res[(long)row*Nn + col];
            Cf[(long)row*Nn + col] = val;
          }
        }
      }
    }
  }
}

// ---------------- fp32 GEMM (head only: 8 rows) ----------------
__global__ __launch_bounds__(256) void gemm_k(
    const float* __restrict__ A, long lda,
    const float* __restrict__ Bw, long ldb,
    const float* __restrict__ bias,
    float* __restrict__ Cf,
    int M, int Nn, int K)
{
  __shared__ float As[16][64];
  __shared__ float Bs[16][64];
  int tid = threadIdx.x;
  int tx = tid & 15, ty = tid >> 4;
  int rowBlk = blockIdx.x * 64, colBlk = blockIdx.y * 64;
  int am = tid >> 2, ak = (tid & 3) * 4;
  int bk = tid >> 4, bc = (tid & 15) * 4;
  float acc[4][4];
  #pragma unroll
  for (int i = 0; i < 4; i++)
    #pragma unroll
    for (int j = 0; j < 4; j++) acc[i][j] = 0.f;

  for (int kt = 0; kt < K; kt += 16){
    float4 av = make_float4(0.f, 0.f, 0.f, 0.f);
    int ar = rowBlk + am;
    if (ar < M) av = *(const float4*)(A + (long)ar*lda + kt + ak);
    As[ak+0][am] = av.x; As[ak+1][am] = av.y; As[ak+2][am] = av.z; As[ak+3][am] = av.w;
    float4 bv4 = *(const float4*)(Bw + (long)(kt + bk)*ldb + colBlk + bc);
    Bs[bk][bc+0] = bv4.x; Bs[bk][bc+1] = bv4.y;
    Bs[bk][bc+2] = bv4.z; Bs[bk][bc+3] = bv4.w;
    __syncthreads();
    #pragma unroll
    for (int kk = 0; kk < 16; kk++){
      float4 a4 = *(const float4*)&As[kk][ty*4];
      float4 b4 = *(const float4*)&Bs[kk][tx*4];
      acc[0][0] += a4.x*b4.x; acc[0][1] += a4.x*b4.y; acc[0][2] += a4.x*b4.z; acc[0][3] += a4.x*b4.w;
      acc[1][0] += a4.y*b4.x; acc[1][1] += a4.y*b4.y; acc[1][2] += a4.y*b4.z; acc[1][3] += a4.y*b4.w;
      acc[2][0] += a4.z*b4.x; acc[2][1] += a4.z*b4.y; acc[2][2] += a4.z*b4.z; acc[2][3] += a4.z*b4.w;
      acc[3][0] += a4.w*b4.x; acc[3][1] += a4.w*b4.y; acc[3][2] += a4.w*b4.z; acc[3][3] += a4.w*b4.w;
    }
    __syncthreads();
  }
  int r0 = rowBlk + ty*4, c0 = colBlk + tx*4;
  float bz[4];
  #pragma unroll
  for (int j = 0; j < 4; j++) bz[j] = bias[c0 + j];
  #pragma unroll
  for (int i = 0; i < 4; i++){
    int r = r0 + i;
    if (r < M){
      #pragma unroll
      for (int j = 0; j < 4; j++)
        Cf[(long)r*Nn + c0 + j] = acc[i][j] + bz[j];
    }
  }
}

// ---------------- kmax via MFMA (k slice of bf16 qkv) ----------------
__global__ __launch_bounds__(256) void kmax2_k(const unsigned short* __restrict__ qkvb,
    const unsigned short* __restrict__ projb, unsigned* __restrict__ kmaxb)
{
  __shared__ __attribute__((aligned(16))) unsigned short ks[64*40];
  __shared__ float red[4];
  int t = blockIdx.x, h = blockIdx.y, b = blockIdx.z;
  int tid = threadIdx.x, w = tid >> 6, lane = tid & 63;
  int fr = lane & 15, fq = lane >> 4, fk = fq*8;
  int n0 = t*64;
  {
    int tok = tid >> 2, d8 = (tid & 3)*8;
    int n = n0 + tok;
    bool vld = (n < N_);
    s8v kv8 = vld ? *(const s8v*)(qkvb + ((long)(b*N_ + n))*QS + 256 + h*DH + d8)
                  : (s8v){0,0,0,0,0,0,0,0};
    *(s8v*)&ks[tok*40 + d8] = kv8;
  }
  __syncthreads();
  s8v bk_ = *(s8v*)&ks[(w*16 + fr)*40 + fk];
  float mx = -INFINITY;
  int n_ = w*16 + fr;
  bool nv = (n0 + n_ < N_);
  #pragma unroll
  for (int mt = 0; mt < 7; mt++){
    s8v ap = *(const s8v*)(projb + (mt*16 + fr)*32 + fk);
    f4v z = (f4v){0.f,0.f,0.f,0.f};
    f4v xd = __builtin_amdgcn_mfma_f32_16x16x32_bf16(ap, bk_, z, 0, 0, 0);
    #pragma unroll
    for (int j = 0; j < 4; j++){
      int m = mt*16 + fq*4 + j;
      float v = (nv && m < M_) ? xd[j]*DN : -INFINITY;
      mx = fmaxf(mx, v);
    }
  }
  #pragma unroll
  for (int mk = 1; mk < 64; mk <<= 1) mx = fmaxf(mx, __shfl_xor(mx, mk));
  if (lane == 0) red[w] = mx;
  __syncthreads();
  if (tid == 0){
    float g = fmaxf(fmaxf(red[0], red[1]), fmaxf(red[2], red[3]));
    atomicMax(kmaxb, floatToOrdered(g));
  }
}

// ---------------- fused ctx via double MFMA (bf16 qkv) ----------------
__global__ __launch_bounds__(256) void fctx_k(const unsigned short* __restrict__ qkvb,
    const unsigned short* __restrict__ projb,
    const unsigned* __restrict__ kmaxb, float* __restrict__ partials)
{
  __shared__ __attribute__((aligned(16))) unsigned short ks[64*40];
  __shared__ __attribute__((aligned(16))) unsigned short vt[48*72];
  __shared__ __attribute__((aligned(16))) unsigned short kps[112*72];
  __shared__ float diags[64];
  int c = blockIdx.x, h = blockIdx.y, b = blockIdx.z;
  int tid = threadIdx.x, w = tid >> 6, lane = tid & 63;
  int fr = lane & 15, fq = lane >> 4, fk = fq*8;
  float kmax = orderedToFloat(kmaxb[0]);

  for (int i = tid; i < 15*72; i += 256) vt[33*72 + i] = 0;
  if (tid < 64) vt[32*72 + tid] = f2us(1.0f);

  s8v ap[7];
  #pragma unroll
  for (int mt = 0; mt < 7; mt++)
    ap[mt] = *(const s8v*)(projb + (mt*16 + fr)*32 + fk);

  int mt0 = w, mt1 = w + 4;
  f4v acc0[3], acc1[3];
  #pragma unroll
  for (int dt = 0; dt < 3; dt++){ acc0[dt] = (f4v){0.f,0.f,0.f,0.f}; acc1[dt] = (f4v){0.f,0.f,0.f,0.f}; }

  int stok = tid >> 2, sd8 = (tid & 3)*8;
  for (int t = c; t < NTILES; t += NC){
    int n0 = t*64;
    __syncthreads();
    {
      int n = n0 + stok;
      bool vld = (n < N_);
      long gb = ((long)(b*N_ + (vld ? n : 0)))*QS + h*DH + sd8;
      s8v kv8 = vld ? *(const s8v*)(qkvb + gb + 256) : (s8v){0,0,0,0,0,0,0,0};
      s8v vv8 = vld ? *(const s8v*)(qkvb + gb + 512) : (s8v){0,0,0,0,0,0,0,0};
      *(s8v*)&ks[stok*40 + sd8] = kv8;
      #pragma unroll
      for (int j = 0; j < 8; j++)
        vt[(sd8 + j)*72 + stok] = (unsigned short)vv8[j];
      float sq = 0.f;
      #pragma unroll
      for (int j = 0; j < 8; j++){
        float kx = us2f((unsigned short)kv8[j]);
        sq += kx*kx;
      }
      sq += __shfl_xor(sq, 1); sq += __shfl_xor(sq, 2);
      if ((tid & 3) == 0) diags[stok] = 0.5f * DN2 * sq;
    }
    __syncthreads();
    s8v bk_ = *(s8v*)&ks[(w*16 + fr)*40 + fk];
    int n_ = w*16 + fr;
    bool nv = (n0 + n_ < N_);
    float dgn = diags[n_];
    #pragma unroll
    for (int mt = 0; mt < 7; mt++){
      f4v z = (f4v){0.f,0.f,0.f,0.f};
      f4v xd = __builtin_amdgcn_mfma_f32_16x16x32_bf16(ap[mt], bk_, z, 0, 0, 0);
      #pragma unroll
      for (int j = 0; j < 4; j++){
        float kp = nv ? RATIO*(expf(xd[j]*DN - dgn - kmax) + 1e-3f) : 0.f;
        kps[(mt*16 + fq*4 + j)*72 + n_] = f2us(kp);
      }
    }
    __syncthreads();
    #pragma unroll
    for (int kst = 0; kst < 2; kst++){
      int ko = kst*32 + fk;
      s8v b0 = *(s8v*)&vt[( 0 + fr)*72 + ko];
      s8v b1 = *(s8v*)&vt[(16 + fr)*72 + ko];
      s8v b2 = *(s8v*)&vt[(32 + fr)*72 + ko];
      s8v a0 = *(s8v*)&kps[(mt0*16 + fr)*72 + ko];
      acc0[0] = __builtin_amdgcn_mfma_f32_16x16x32_bf16(a0, b0, acc0[0], 0, 0, 0);
      acc0[1] = __builtin_amdgcn_mfma_f32_16x16x32_bf16(a0, b1, acc0[1], 0, 0, 0);
      acc0[2] = __builtin_amdgcn_mfma_f32_16x16x32_bf16(a0, b2, acc0[2], 0, 0, 0);
      if (mt1 < 7){
        s8v a1 = *(s8v*)&kps[(mt1*16 + fr)*72 + ko];
        acc1[0] = __builtin_amdgcn_mfma_f32_16x16x32_bf16(a1, b0, acc1[0], 0, 0, 0);
        acc1[1] = __builtin_amdgcn_mfma_f32_16x16x32_bf16(a1, b1, acc1[1], 0, 0, 0);
        acc1[2] = __builtin_amdgcn_mfma_f32_16x16x32_bf16(a1, b2, acc1[2], 0, 0, 0);
      }
    }
  }
  long pb = ((long)c*64 + (b*H_ + h))*CTXE;
  #pragma unroll
  for (int dt = 0; dt < 3; dt++){
    int d = dt*16 + fr;
    if (d < 33){
      #pragma unroll
      for (int j = 0; j < 4; j++){
        int m0 = mt0*16 + fq*4 + j;
        if (m0 < M_) partials[pb + m0*33 + d] = acc0[dt][j];
        if (mt1 < 7){
          int m1 = mt1*16 + fq*4 + j;
          if (m1 < M_) partials[pb + m1*33 + d] = acc1[dt][j];
        }
      }
    }
  }
}

// ---------------- ctx partial reduce (coalesced) ----------------
__global__ __launch_bounds__(256) void ctxred2_k(const float* __restrict__ partials,
                                                 float* __restrict__ ctxf)
{
  int i = blockIdx.x*256 + threadIdx.x;
  if (i >= CTXN2) return;
  float s = 0.f;
  #pragma unroll
  for (int c = 0; c < NC; c++) s += partials[(long)c*CTXN2 + i];
  ctxf[i] = s;
}

// ---------------- attn v3: full-MFMA query side (bf16 qkv; reads reduced ctxf) ----------------
__global__ __launch_bounds__(256) void attn3_k(const unsigned short* __restrict__ qkvb,
    const float* __restrict__ ctxf, const unsigned short* __restrict__ projb,
    unsigned short* __restrict__ ob)
{
  __shared__ __attribute__((aligned(16))) unsigned short qs[64*40];
  __shared__ __attribute__((aligned(16))) unsigned short qps[64*136];
  __shared__ __attribute__((aligned(16))) unsigned short cst[48*136];
  __shared__ float diags[64];
  __shared__ float dens[64];
  int t = blockIdx.x, h = blockIdx.y, b = blockIdx.z;
  int tid = threadIdx.x, w = tid >> 6, lane = tid & 63;
  int fr = lane & 15, fq = lane >> 4, fk = fq*8;
  int n0 = t*64;
  long cbase = ((long)(b*H_ + h))*CTXE;

  for (int i = tid; i < 64*16; i += 256)
    qps[(i >> 4)*136 + 112 + (i & 15)] = 0;

  {
    int tok = tid >> 2, d8 = (tid & 3)*8;
    int n = n0 + tok;
    bool vld = (n < N_);
    s8v qv8 = vld ? *(const s8v*)(qkvb + ((long)(b*N_ + n))*QS + h*DH + d8)
                  : (s8v){0,0,0,0,0,0,0,0};
    *(s8v*)&qs[tok*40 + d8] = qv8;
    float sq = 0.f;
    #pragma unroll
    for (int j = 0; j < 8; j++){
      float qx = us2f((unsigned short)qv8[j]);
      sq += qx*qx;
    }
    sq += __shfl_xor(sq, 1); sq += __shfl_xor(sq, 2);
    if ((tid & 3) == 0) diags[tok] = 0.5f * DN2 * sq;
  }
  for (int i = tid; i < 48*128; i += 256){
    int d = i >> 7, m = i & 127;
    float v = (d < 33 && m < M_) ? ctxf[cbase + (long)m*33 + d] : 0.f;
    cst[d*136 + m] = f2us(v);
  }
  __syncthreads();

  s8v bq_ = *(s8v*)&qs[(w*16 + fr)*40 + fk];
  int n_ = w*16 + fr;
  bool nv = (n0 + n_ < N_);
  float dgn = diags[n_];
  f4v xdv[7];
  #pragma unroll
  for (int mt = 0; mt < 7; mt++){
    s8v ap = *(const s8v*)(projb + (mt*16 + fr)*32 + fk);
    f4v z = (f4v){0.f,0.f,0.f,0.f};
    xdv[mt] = __builtin_amdgcn_mfma_f32_16x16x32_bf16(ap, bq_, z, 0, 0, 0);
  }
  float mx = -INFINITY;
  #pragma unroll
  for (int mt = 0; mt < 7; mt++)
    #pragma unroll
    for (int j = 0; j < 4; j++){
      int m = mt*16 + fq*4 + j;
      if (m < M_) mx = fmaxf(mx, xdv[mt][j]*DN);
    }
  mx = fmaxf(mx, __shfl_xor(mx, 16));
  mx = fmaxf(mx, __shfl_xor(mx, 32));
  #pragma unroll
  for (int mt = 0; mt < 7; mt++)
    #pragma unroll
    for (int j = 0; j < 4; j++){
      int m = mt*16 + fq*4 + j;
      float qp = (nv && m < M_) ? RATIO*(expf(xdv[mt][j]*DN - dgn - mx) + 1e-3f) : 0.f;
      qps[n_*136 + m] = f2us(qp);
    }
  __syncthreads();

  f4v acc[3];
  acc[0] = (f4v){0,0,0,0}; acc[1] = (f4v){0,0,0,0}; acc[2] = (f4v){0,0,0,0};
  #pragma unroll
  for (int ks = 0; ks < 4; ks++){
    int ko = ks*32 + fk;
    s8v bqp = *(s8v*)&qps[(w*16 + fr)*136 + ko];
    #pragma unroll
    for (int dt = 0; dt < 3; dt++){
      s8v ac = *(s8v*)&cst[(dt*16 + fr)*136 + ko];
      acc[dt] = __builtin_amdgcn_mfma_f32_16x16x32_bf16(ac, bqp, acc[dt], 0, 0, 0);
    }
  }
  if (fq == 0) dens[n_] = acc[2][0];
  __syncthreads();
  float dinv = 1.0f / dens[n_];
  if (nv){
    long obase = ((long)(b*N_ + n0 + n_))*D_ + h*DH;
    #pragma unroll
    for (int dt = 0; dt < 2; dt++){
      ushort4 wv;
      wv.x = f2us(acc[dt][0]*dinv);
      wv.y = f2us(acc[dt][1]*dinv);
      wv.z = f2us(acc[dt][2]*dinv);
      wv.w = f2us(acc[dt][3]*dinv);
      *(ushort4*)(ob + obase + dt*16 + fq*4) = wv;
    }
  }
}

// ---------------- host ----------------
extern "C" void kernel_launch(void* const* d_in, const int* in_sizes, int n_in,
                              void* d_out, int out_size, void* d_ws, size_t ws_size,
                              hipStream_t stream)
{
  const float* expr = (const float*)d_in[0];
  const float* temb = (const float*)d_in[1];
  const float* cls  = (const float*)d_in[2];
  const float* ln1g = (const float*)d_in[3];
  const float* ln1b = (const float*)d_in[4];
  const float* Wq   = (const float*)d_in[5];
  const float* bq   = (const float*)d_in[6];
  const float* Wk   = (const float*)d_in[7];
  const float* bk   = (const float*)d_in[8];
  const float* Wv   = (const float*)d_in[9];
  const float* bv   = (const float*)d_in[10];
  const float* Wo   = (const float*)d_in[11];
  const float* bo   = (const float*)d_in[12];
  const float* ln2g = (const float*)d_in[13];
  const float* ln2b = (const float*)d_in[14];
  const float* W1   = (const float*)d_in[15];
  const float* b1   = (const float*)d_in[16];
  const float* W2   = (const float*)d_in[17];
  const float* b2   = (const float*)d_in[18];
  const float* proj = (const float*)d_in[19];
  const float* Wp   = (const float*)d_in[20];
  const float* bp   = (const float*)d_in[21];
  (void)in_sizes; (void)n_in; (void)out_size; (void)ws_size;

  char* w = (char*)d_ws;
  size_t off = 0;
  auto alloc = [&](size_t bytes) -> char* {
    char* p = w + off;
    off = (off + bytes + 255) & ~(size_t)255;
    return p;
  };
  float*    selected = (float*)alloc((size_t)B_*KSEL*4);
  float*    bsum     = (float*)alloc(B_*4);
  float*    bv0      = (float*)alloc(B_*4);
  float*    emaxp    = (float*)alloc(4);
  unsigned* kmaxb    = (unsigned*)alloc(DEPTH_*4);
  float*    ctxf     = (float*)alloc((size_t)CTXN2*4);
  float*          x  = (float*)alloc((size_t)BN_*D_*4);
  unsigned short* h  = (unsigned short*)alloc((size_t)BN_*D_*2);
  unsigned short* qkvb = (unsigned short*)alloc((size_t)BN_*DFF_*2);  // qkv bf16 (stride QS); ffi aliases (stride 1024)
  float*     partials = (float*)alloc((size_t)NC*CTXN2*4);
  unsigned short* Wqkvt = (unsigned short*)alloc((size_t)DEPTH_*QS*D_*2);
  unsigned short* Wot = (unsigned short*)alloc((size_t)DEPTH_*D_*D_*2);
  unsigned short* W1t = (unsigned short*)alloc((size_t)DEPTH_*D_*DFF_*2);
  unsigned short* W2t = (unsigned short*)alloc((size_t)DEPTH_*DFF_*D_*2);
  unsigned short* projb = (unsigned short*)alloc((size_t)DEPTH_*112*32*2);
  float*    bqkv     = (float*)alloc((size_t)DEPTH_*QS*4);
  unsigned short* ffi = qkvb;                  // bf16 [BN][1024] aliases qkv (dead during FFN)

  // all one-time weight/proj/bias conversions in ONE dispatch
  prep_k<<<4620, 256, 0, stream>>>(Wq, Wk, Wv, Wo, W1, W2,
                                   Wqkvt, Wot, W1t, W2t,
                                   proj, projb, kmaxb, bq, bk, bv, bqkv);

  topk_k<<<B_, 1024, 0, stream>>>(expr, selected, bsum, bv0);
  emax_k<<<1, 64, 0, stream>>>(bsum, bv0, emaxp);
  embed_k<<<BN_/4, 256, 0, stream>>>(selected, bsum, emaxp, temb, cls, x);

  for (int L = 0; L < DEPTH_; L++){
    const unsigned short* pjb = projb + (size_t)L*112*32;
    ln_k<<<BN_/4, 256, 0, stream>>>(x, h, ln1g + L*D_, ln1b + L*D_);
    bgemm_k<0,0,1><<<dim3(6,129), 256, 0, stream>>>(h, D_, Wqkvt + (size_t)L*QS*D_, bqkv + (size_t)L*QS, nullptr, nullptr, qkvb, BN_, QS, D_);
    kmax2_k<<<dim3(NTILES, H_, B_), 256, 0, stream>>>(qkvb, pjb, kmaxb + L);
    fctx_k<<<dim3(NC, H_, B_), 256, 0, stream>>>(qkvb, pjb, kmaxb + L, partials);
    ctxred2_k<<<(CTXN2 + 255)/256, 256, 0, stream>>>(partials, ctxf);
    attn3_k<<<dim3(NTILES, H_, B_), 256, 0, stream>>>(qkvb, ctxf, pjb, h);   // o -> h (bf16)
    bgemm_k<0,1,0><<<dim3(2,129), 256, 0, stream>>>(h, D_, Wot + (size_t)L*D_*D_, bo + L*D_, x, x, nullptr, BN_, D_, D_);
    ln_k<<<BN_/4, 256, 0, stream>>>(x, h, ln2g + L*D_, ln2b + L*D_);
    bgemm_k<1,0,1><<<dim3(8,129), 256, 0, stream>>>(h, D_, W1t + (size_t)L*D_*DFF_, b1 + L*DFF_, nullptr, nullptr, ffi, BN_, DFF_, D_);
    bgemm_k<0,1,0><<<dim3(2,129), 256, 0, stream>>>(ffi, DFF_, W2t + (size_t)L*DFF_*D_, b2 + L*D_, x, x, nullptr, BN_, D_, DFF_);
  }
  gemm_k<<<dim3(1,4), 256, 0, stream>>>(x, (long)N_*D_, Wp, D_, bp,
                                        (float*)d_out, B_, D_, D_);
}